// Round 1
// baseline (1067.806 us; speedup 1.0000x reference)
//
#include <hip/hip_runtime.h>

#define NNODES 50000
#define NEDGES 800000
#define DIM 128
#define NGRAPHS 128
#define OUT1_STRIDE 384   // 3 layers * 128 concat along axis 1
#define OUT0_ELEMS (NGRAPHS * OUT1_STRIDE)

// ---------- CSR build ----------
__global__ void k_count(const int* __restrict__ dst, int* __restrict__ rowcnt, int E) {
    int e = blockIdx.x * blockDim.x + threadIdx.x;
    if (e < E) atomicAdd(&rowcnt[dst[e]], 1);
}

__global__ void k_dinv(const int* __restrict__ rowcnt, float* __restrict__ dinv, int N) {
    int i = blockIdx.x * blockDim.x + threadIdx.x;
    if (i < N) dinv[i] = rsqrtf((float)rowcnt[i] + 1.0f);  // +1 for self-loop
}

// single-block exclusive scan of rowcnt[0..n) -> rowptr[0..n]
__global__ void k_scan(const int* __restrict__ cnt, int* __restrict__ rowptr, int n) {
    __shared__ int sums[1024];
    int tid = threadIdx.x;
    int chunk = (n + 1023) >> 10;
    int start = tid * chunk;
    int end = min(start + chunk, n);
    int s = 0;
    for (int i = start; i < end; ++i) s += cnt[i];
    sums[tid] = s;
    __syncthreads();
    for (int off = 1; off < 1024; off <<= 1) {
        int v = (tid >= off) ? sums[tid - off] : 0;
        __syncthreads();
        sums[tid] += v;
        __syncthreads();
    }
    int run = sums[tid] - s;  // exclusive base for this chunk
    for (int i = start; i < end; ++i) { rowptr[i] = run; run += cnt[i]; }
    if (tid == 0) rowptr[n] = sums[1023];
}

__global__ void k_fill(const int* __restrict__ src, const int* __restrict__ dst,
                       const int* __restrict__ rowptr, int* __restrict__ fillcnt,
                       const float* __restrict__ dinv,
                       int* __restrict__ csr_src, float* __restrict__ csr_norm, int E) {
    int e = blockIdx.x * blockDim.x + threadIdx.x;
    if (e < E) {
        int d = dst[e], s = src[e];
        int pos = rowptr[d] + atomicAdd(&fillcnt[d], 1);
        csr_src[pos]  = s;
        csr_norm[pos] = dinv[s] * dinv[d];
    }
}

__global__ void k_counts(const int* __restrict__ batch, float* __restrict__ counts, int N) {
    int i = blockIdx.x * blockDim.x + threadIdx.x;
    if (i < N) atomicAdd(&counts[batch[i]], 1.0f);
}

// ---------- GEMM: out[M x 128] = A[M x 128, row stride lda] @ W[128 x 128] ----------
__global__ __launch_bounds__(256) void k_gemm(const float* __restrict__ A, int lda,
                                              const float* __restrict__ W,
                                              float* __restrict__ out, int M) {
    __shared__ float wt[64 * 128];  // half-K tile of W
    __shared__ float at[8 * 128];   // 8 rows of A, full K
    int tid = threadIdx.x;
    int r  = tid >> 5;   // 0..7 row within tile
    int cg = tid & 31;   // col group (4 cols)
    int row0 = blockIdx.x * 8;
    {
        int ar = tid >> 5;
        int ac = (tid & 31) * 4;
        int grow = row0 + ar;
        float4 v = make_float4(0, 0, 0, 0);
        if (grow < M) v = *(const float4*)(A + (size_t)grow * lda + ac);
        *(float4*)(at + ar * 128 + ac) = v;
    }
    float4 acc = make_float4(0, 0, 0, 0);
    for (int kt = 0; kt < 2; ++kt) {
        __syncthreads();  // at visible (first iter) / wt reuse safe (second iter)
        {
            const float4* Wk = (const float4*)(W + kt * 64 * 128);
            float4* wt4 = (float4*)wt;
#pragma unroll
            for (int j = 0; j < 8; ++j) {
                int idx = j * 256 + tid;   // 2048 float4s total
                wt4[idx] = Wk[idx];
            }
        }
        __syncthreads();
#pragma unroll 8
        for (int k = 0; k < 64; ++k) {
            float a = at[r * 128 + kt * 64 + k];
            float4 w = *(const float4*)(wt + k * 128 + cg * 4);
            acc.x += a * w.x; acc.y += a * w.y; acc.z += a * w.z; acc.w += a * w.w;
        }
    }
    int grow = row0 + r;
    if (grow < M) *(float4*)(out + (size_t)grow * 128 + cg * 4) = acc;
}

// ---------- fused aggregate + bias + relu + write out1 + pool atomics ----------
// one wave per node; lane handles 2 contiguous channels
__global__ __launch_bounds__(256) void k_agg(const float* __restrict__ hW,
                                             const int* __restrict__ rowptr,
                                             const int* __restrict__ csr_src,
                                             const float* __restrict__ csr_norm,
                                             const float* __restrict__ dinv,
                                             const float* __restrict__ bias,
                                             const int* __restrict__ batch,
                                             float* __restrict__ out1,
                                             float* __restrict__ pool,
                                             int N, int layer) {
    int wave = threadIdx.x >> 6;
    int lane = threadIdx.x & 63;
    int n = blockIdx.x * 4 + wave;
    if (n >= N) return;
    float din = dinv[n];
    float2 h0 = ((const float2*)(hW + (size_t)n * DIM))[lane];
    float2 acc;
    acc.x = h0.x * din * din;   // self-loop contribution
    acc.y = h0.y * din * din;
    int beg = rowptr[n], end = rowptr[n + 1];
    for (int e = beg; e < end; ++e) {
        int s   = csr_src[e];
        float w = csr_norm[e];
        float2 hv = ((const float2*)(hW + (size_t)s * DIM))[lane];
        acc.x += w * hv.x;
        acc.y += w * hv.y;
    }
    float2 b = ((const float2*)bias)[lane];
    float ox = fmaxf(acc.x + b.x, 0.0f);
    float oy = fmaxf(acc.y + b.y, 0.0f);
    size_t o1 = (size_t)n * OUT1_STRIDE + layer * DIM + lane * 2;
    *(float2*)(out1 + o1) = make_float2(ox, oy);
    int g = batch[n];
    size_t po = (size_t)g * OUT1_STRIDE + layer * DIM + lane * 2;
    atomicAdd(&pool[po],     ox);
    atomicAdd(&pool[po + 1], oy);
}

__global__ void k_div(float* __restrict__ pool, const float* __restrict__ counts, int total) {
    int i = blockIdx.x * blockDim.x + threadIdx.x;
    if (i < total) {
        int g = i / OUT1_STRIDE;
        pool[i] /= fmaxf(counts[g], 1.0f);
    }
}

extern "C" void kernel_launch(void* const* d_in, const int* in_sizes, int n_in,
                              void* d_out, int out_size, void* d_ws, size_t ws_size,
                              hipStream_t stream) {
    const float* x     = (const float*)d_in[0];
    const int*   ei    = (const int*)d_in[1];
    const int*   batch = (const int*)d_in[2];
    const float* W0 = (const float*)d_in[3];
    const float* b0 = (const float*)d_in[4];
    const float* W1 = (const float*)d_in[5];
    const float* b1 = (const float*)d_in[6];
    const float* W2 = (const float*)d_in[7];
    const float* b2 = (const float*)d_in[8];
    (void)n_in; (void)ws_size; (void)out_size;

    const int E = in_sizes[1] / 2;
    const int N = in_sizes[2];
    const int* src = ei;
    const int* dst = ei + E;

    char* ws = (char*)d_ws;
    float* hW       = (float*)ws; ws += (size_t)NNODES * DIM * 4;
    float* dinv     = (float*)ws; ws += 50016 * 4;
    int*   rowcnt   = (int*)ws;   ws += 50016 * 4;
    int*   fillcnt  = (int*)ws;   ws += 50016 * 4;
    int*   rowptr   = (int*)ws;   ws += 50016 * 4;
    int*   csr_src  = (int*)ws;   ws += (size_t)NEDGES * 4;
    float* csr_norm = (float*)ws; ws += (size_t)NEDGES * 4;
    float* counts   = (float*)ws; ws += 256 * 4;

    float* out0 = (float*)d_out;                 // [128, 384] pooled
    float* out1 = (float*)d_out + OUT0_ELEMS;    // [50000, 384] per-layer features

    hipMemsetAsync(rowcnt,  0, (size_t)N * 4, stream);
    hipMemsetAsync(fillcnt, 0, (size_t)N * 4, stream);
    hipMemsetAsync(counts,  0, 256 * 4, stream);
    hipMemsetAsync(out0,    0, (size_t)OUT0_ELEMS * 4, stream);

    k_count<<<(E + 255) / 256, 256, 0, stream>>>(dst, rowcnt, E);
    k_dinv <<<(N + 255) / 256, 256, 0, stream>>>(rowcnt, dinv, N);
    k_scan <<<1, 1024, 0, stream>>>(rowcnt, rowptr, N);
    k_fill <<<(E + 255) / 256, 256, 0, stream>>>(src, dst, rowptr, fillcnt, dinv,
                                                 csr_src, csr_norm, E);
    k_counts<<<(N + 255) / 256, 256, 0, stream>>>(batch, counts, N);

    const float* Ws[3] = {W0, W1, W2};
    const float* bs[3] = {b0, b1, b2};
    for (int l = 0; l < 3; ++l) {
        const float* Ain = (l == 0) ? x : (out1 + (size_t)(l - 1) * DIM);
        int lda          = (l == 0) ? DIM : OUT1_STRIDE;
        k_gemm<<<(N + 7) / 8, 256, 0, stream>>>(Ain, lda, Ws[l], hW, N);
        k_agg <<<(N + 3) / 4, 256, 0, stream>>>(hW, rowptr, csr_src, csr_norm, dinv,
                                                bs[l], batch, out1, out0, N, l);
    }
    k_div<<<(OUT0_ELEMS + 255) / 256, 256, 0, stream>>>(out0, counts, OUT0_ELEMS);
}

// Round 2
// 928.472 us; speedup vs baseline: 1.1501x; 1.1501x over previous
//
#include <hip/hip_runtime.h>

#define NNODES 50000
#define NEDGES 800000
#define DIM 128
#define NGRAPHS 128
#define OUT1_STRIDE 384   // 3 layers * 128 concat along axis 1
#define OUT0_ELEMS (NGRAPHS * OUT1_STRIDE)

// ---------- CSR build ----------
__global__ void k_count(const int* __restrict__ dst, int* __restrict__ rowcnt, int E) {
    int e = blockIdx.x * blockDim.x + threadIdx.x;
    if (e < E) atomicAdd(&rowcnt[dst[e]], 1);
}

__global__ void k_dinv(const int* __restrict__ rowcnt, float* __restrict__ dinv, int N) {
    int i = blockIdx.x * blockDim.x + threadIdx.x;
    if (i < N) dinv[i] = rsqrtf((float)rowcnt[i] + 1.0f);  // +1 for self-loop
}

// single-block exclusive scan of rowcnt[0..n) -> rowptr[0..n]
__global__ void k_scan(const int* __restrict__ cnt, int* __restrict__ rowptr, int n) {
    __shared__ int sums[1024];
    int tid = threadIdx.x;
    int chunk = (n + 1023) >> 10;
    int start = tid * chunk;
    int end = min(start + chunk, n);
    int s = 0;
    for (int i = start; i < end; ++i) s += cnt[i];
    sums[tid] = s;
    __syncthreads();
    for (int off = 1; off < 1024; off <<= 1) {
        int v = (tid >= off) ? sums[tid - off] : 0;
        __syncthreads();
        sums[tid] += v;
        __syncthreads();
    }
    int run = sums[tid] - s;  // exclusive base for this chunk
    for (int i = start; i < end; ++i) { rowptr[i] = run; run += cnt[i]; }
    if (tid == 0) rowptr[n] = sums[1023];
}

__global__ void k_fill(const int* __restrict__ src, const int* __restrict__ dst,
                       const int* __restrict__ rowptr, int* __restrict__ fillcnt,
                       const float* __restrict__ dinv,
                       int* __restrict__ csr_src, float* __restrict__ csr_norm, int E) {
    int e = blockIdx.x * blockDim.x + threadIdx.x;
    if (e < E) {
        int d = dst[e], s = src[e];
        int pos = rowptr[d] + atomicAdd(&fillcnt[d], 1);
        csr_src[pos]  = s;
        csr_norm[pos] = dinv[s] * dinv[d];
    }
}

__global__ void k_counts(const int* __restrict__ batch, float* __restrict__ counts, int N) {
    int i = blockIdx.x * blockDim.x + threadIdx.x;
    if (i < N) atomicAdd(&counts[batch[i]], 1.0f);
}

// ---------- GEMM: out[M x 128] = A[M x 128, row stride lda] @ W[128 x 128] ----------
// 32 rows per block; full W (64 KB) staged in LDS once per block.
__global__ __launch_bounds__(256) void k_gemm(const float* __restrict__ A, int lda,
                                              const float* __restrict__ W,
                                              float* __restrict__ out, int M) {
    __shared__ float wt[128 * 128];  // 64 KB
    __shared__ float at[32 * 128];   // 16 KB
    int tid = threadIdx.x;
    int row0 = blockIdx.x * 32;
    // stage W: 4096 float4 / 256 threads = 16 each
#pragma unroll
    for (int i = 0; i < 16; ++i)
        ((float4*)wt)[i * 256 + tid] = ((const float4*)W)[i * 256 + tid];
    // stage A tile: 1024 float4 / 256 threads = 4 each
#pragma unroll
    for (int i = 0; i < 4; ++i) {
        int idx = i * 256 + tid;      // float4 index
        int ar  = idx >> 5;           // 32 float4 per row
        int ac  = (idx & 31) * 4;
        int grow = row0 + ar;
        float4 v = make_float4(0, 0, 0, 0);
        if (grow < M) v = *(const float4*)(A + (size_t)grow * lda + ac);
        *(float4*)(at + ar * 128 + ac) = v;
    }
    __syncthreads();
    int rg = tid >> 5;   // 0..7 → rows rg*4 .. rg*4+3
    int cg = tid & 31;   // cols cg*4 .. cg*4+3
    float4 acc[4] = {};
#pragma unroll 4
    for (int k = 0; k < 128; ++k) {
        float4 wv = *(const float4*)(wt + k * 128 + cg * 4);
#pragma unroll
        for (int i = 0; i < 4; ++i) {
            float a = at[(rg * 4 + i) * 128 + k];
            acc[i].x += a * wv.x; acc[i].y += a * wv.y;
            acc[i].z += a * wv.z; acc[i].w += a * wv.w;
        }
    }
#pragma unroll
    for (int i = 0; i < 4; ++i) {
        int grow = row0 + rg * 4 + i;
        if (grow < M) *(float4*)(out + (size_t)grow * 128 + cg * 4) = acc[i];
    }
}

// ---------- fused aggregate + bias + relu + write out1 + pool atomics ----------
// one wave per node; lane handles 2 contiguous channels.
// Edge (src,norm) pairs are batch-preloaded by lanes and broadcast via shfl,
// gathers unrolled x4 for memory-level parallelism.
__global__ __launch_bounds__(256) void k_agg(const float* __restrict__ hW,
                                             const int* __restrict__ rowptr,
                                             const int* __restrict__ csr_src,
                                             const float* __restrict__ csr_norm,
                                             const float* __restrict__ dinv,
                                             const float* __restrict__ bias,
                                             const int* __restrict__ batch,
                                             float* __restrict__ out1,
                                             float* __restrict__ pool,
                                             int N, int layer) {
    int wave = threadIdx.x >> 6;
    int lane = threadIdx.x & 63;
    int n = blockIdx.x * 4 + wave;
    if (n >= N) return;
    float din = dinv[n];
    float2 h0 = ((const float2*)(hW + (size_t)n * DIM))[lane];
    float ax = h0.x * din * din;   // self-loop contribution
    float ay = h0.y * din * din;
    int beg = rowptr[n], end = rowptr[n + 1];
    for (int base = beg; base < end; base += 64) {
        int cnt = min(64, end - base);
        int eidx = base + lane;
        int   smy = 0;
        float wmy = 0.0f;
        if (eidx < end) { smy = csr_src[eidx]; wmy = csr_norm[eidx]; }
        int j = 0;
        for (; j + 4 <= cnt; j += 4) {
            int   s0 = __shfl(smy, j),     s1 = __shfl(smy, j + 1);
            int   s2 = __shfl(smy, j + 2), s3 = __shfl(smy, j + 3);
            float w0 = __shfl(wmy, j),     w1 = __shfl(wmy, j + 1);
            float w2 = __shfl(wmy, j + 2), w3 = __shfl(wmy, j + 3);
            float2 v0 = ((const float2*)(hW + (size_t)s0 * DIM))[lane];
            float2 v1 = ((const float2*)(hW + (size_t)s1 * DIM))[lane];
            float2 v2 = ((const float2*)(hW + (size_t)s2 * DIM))[lane];
            float2 v3 = ((const float2*)(hW + (size_t)s3 * DIM))[lane];
            ax += w0 * v0.x + w1 * v1.x + w2 * v2.x + w3 * v3.x;
            ay += w0 * v0.y + w1 * v1.y + w2 * v2.y + w3 * v3.y;
        }
        for (; j < cnt; ++j) {
            int   ss = __shfl(smy, j);
            float ww = __shfl(wmy, j);
            float2 hv = ((const float2*)(hW + (size_t)ss * DIM))[lane];
            ax += ww * hv.x;
            ay += ww * hv.y;
        }
    }
    float2 b = ((const float2*)bias)[lane];
    float ox = fmaxf(ax + b.x, 0.0f);
    float oy = fmaxf(ay + b.y, 0.0f);
    size_t o1 = (size_t)n * OUT1_STRIDE + layer * DIM + lane * 2;
    *(float2*)(out1 + o1) = make_float2(ox, oy);
    int g = batch[n];
    size_t po = (size_t)g * OUT1_STRIDE + layer * DIM + lane * 2;
    atomicAdd(&pool[po],     ox);
    atomicAdd(&pool[po + 1], oy);
}

__global__ void k_div(float* __restrict__ pool, const float* __restrict__ counts, int total) {
    int i = blockIdx.x * blockDim.x + threadIdx.x;
    if (i < total) {
        int g = i / OUT1_STRIDE;
        pool[i] /= fmaxf(counts[g], 1.0f);
    }
}

extern "C" void kernel_launch(void* const* d_in, const int* in_sizes, int n_in,
                              void* d_out, int out_size, void* d_ws, size_t ws_size,
                              hipStream_t stream) {
    const float* x     = (const float*)d_in[0];
    const int*   ei    = (const int*)d_in[1];
    const int*   batch = (const int*)d_in[2];
    const float* W0 = (const float*)d_in[3];
    const float* b0 = (const float*)d_in[4];
    const float* W1 = (const float*)d_in[5];
    const float* b1 = (const float*)d_in[6];
    const float* W2 = (const float*)d_in[7];
    const float* b2 = (const float*)d_in[8];
    (void)n_in; (void)ws_size; (void)out_size;

    const int E = in_sizes[1] / 2;
    const int N = in_sizes[2];
    const int* src = ei;
    const int* dst = ei + E;

    char* ws = (char*)d_ws;
    float* hW       = (float*)ws; ws += (size_t)NNODES * DIM * 4;
    float* dinv     = (float*)ws; ws += 50016 * 4;
    int*   rowcnt   = (int*)ws;   ws += 50016 * 4;
    int*   fillcnt  = (int*)ws;   ws += 50016 * 4;
    int*   rowptr   = (int*)ws;   ws += 50016 * 4;
    int*   csr_src  = (int*)ws;   ws += (size_t)NEDGES * 4;
    float* csr_norm = (float*)ws; ws += (size_t)NEDGES * 4;
    float* counts   = (float*)ws; ws += 256 * 4;

    float* out0 = (float*)d_out;                 // [128, 384] pooled
    float* out1 = (float*)d_out + OUT0_ELEMS;    // [50000, 384] per-layer features

    hipMemsetAsync(rowcnt,  0, (size_t)N * 4, stream);
    hipMemsetAsync(fillcnt, 0, (size_t)N * 4, stream);
    hipMemsetAsync(counts,  0, 256 * 4, stream);
    hipMemsetAsync(out0,    0, (size_t)OUT0_ELEMS * 4, stream);

    k_count<<<(E + 255) / 256, 256, 0, stream>>>(dst, rowcnt, E);
    k_dinv <<<(N + 255) / 256, 256, 0, stream>>>(rowcnt, dinv, N);
    k_scan <<<1, 1024, 0, stream>>>(rowcnt, rowptr, N);
    k_fill <<<(E + 255) / 256, 256, 0, stream>>>(src, dst, rowptr, fillcnt, dinv,
                                                 csr_src, csr_norm, E);
    k_counts<<<(N + 255) / 256, 256, 0, stream>>>(batch, counts, N);

    const float* Ws[3] = {W0, W1, W2};
    const float* bs[3] = {b0, b1, b2};
    for (int l = 0; l < 3; ++l) {
        const float* Ain = (l == 0) ? x : (out1 + (size_t)(l - 1) * DIM);
        int lda          = (l == 0) ? DIM : OUT1_STRIDE;
        k_gemm<<<(N + 31) / 32, 256, 0, stream>>>(Ain, lda, Ws[l], hW, N);
        k_agg <<<(N + 3) / 4, 256, 0, stream>>>(hW, rowptr, csr_src, csr_norm, dinv,
                                                bs[l], batch, out1, out0, N, l);
    }
    k_div<<<(OUT0_ELEMS + 255) / 256, 256, 0, stream>>>(out0, counts, OUT0_ELEMS);
}

// Round 3
// 578.766 us; speedup vs baseline: 1.8450x; 1.6042x over previous
//
#include <hip/hip_runtime.h>

#define NNODES 50000
#define NEDGES 800000
#define DIM 128
#define NGRAPHS 128
#define OUT1_STRIDE 384   // 3 layers * 128 concat along axis 1
#define OUT0_ELEMS (NGRAPHS * OUT1_STRIDE)

// ---------- CSR build ----------
__global__ void k_count(const int* __restrict__ dst, int* __restrict__ rowcnt, int E) {
    int e = blockIdx.x * blockDim.x + threadIdx.x;
    if (e < E) atomicAdd(&rowcnt[dst[e]], 1);
}

__global__ void k_dinv(const int* __restrict__ rowcnt, float* __restrict__ dinv, int N) {
    int i = blockIdx.x * blockDim.x + threadIdx.x;
    if (i < N) dinv[i] = rsqrtf((float)rowcnt[i] + 1.0f);  // +1 for self-loop
}

// single-block exclusive scan of rowcnt[0..n) -> rowptr[0..n]
__global__ void k_scan(const int* __restrict__ cnt, int* __restrict__ rowptr, int n) {
    __shared__ int sums[1024];
    int tid = threadIdx.x;
    int chunk = (n + 1023) >> 10;
    int start = tid * chunk;
    int end = min(start + chunk, n);
    int s = 0;
    for (int i = start; i < end; ++i) s += cnt[i];
    sums[tid] = s;
    __syncthreads();
    for (int off = 1; off < 1024; off <<= 1) {
        int v = (tid >= off) ? sums[tid - off] : 0;
        __syncthreads();
        sums[tid] += v;
        __syncthreads();
    }
    int run = sums[tid] - s;  // exclusive base for this chunk
    for (int i = start; i < end; ++i) { rowptr[i] = run; run += cnt[i]; }
    if (tid == 0) rowptr[n] = sums[1023];
}

__global__ void k_fill(const int* __restrict__ src, const int* __restrict__ dst,
                       const int* __restrict__ rowptr, int* __restrict__ fillcnt,
                       const float* __restrict__ dinv,
                       int* __restrict__ csr_src, float* __restrict__ csr_norm, int E) {
    int e = blockIdx.x * blockDim.x + threadIdx.x;
    if (e < E) {
        int d = dst[e], s = src[e];
        int pos = rowptr[d] + atomicAdd(&fillcnt[d], 1);
        csr_src[pos]  = s;
        csr_norm[pos] = dinv[s] * dinv[d];
    }
}

// batch is sorted: start[g] = first index with batch[i] >= g, start[NGRAPHS] = N
__global__ void k_bounds(const int* __restrict__ batch, int* __restrict__ start, int N) {
    int g = threadIdx.x;
    if (g > NGRAPHS) return;
    if (g == NGRAPHS) { start[g] = N; return; }
    int lo = 0, hi = N;
    while (lo < hi) {
        int mid = (lo + hi) >> 1;
        if (batch[mid] < g) lo = mid + 1; else hi = mid;
    }
    start[g] = lo;
}

// ---------- GEMM: out[M x 128] = A[M x 128, row stride lda] @ W[128 x 128] ----------
// 32 rows per block; full W (64 KB) staged in LDS once per block.
__global__ __launch_bounds__(256) void k_gemm(const float* __restrict__ A, int lda,
                                              const float* __restrict__ W,
                                              float* __restrict__ out, int M) {
    __shared__ float wt[128 * 128];  // 64 KB
    __shared__ float at[32 * 128];   // 16 KB
    int tid = threadIdx.x;
    int row0 = blockIdx.x * 32;
#pragma unroll
    for (int i = 0; i < 16; ++i)
        ((float4*)wt)[i * 256 + tid] = ((const float4*)W)[i * 256 + tid];
#pragma unroll
    for (int i = 0; i < 4; ++i) {
        int idx = i * 256 + tid;      // float4 index
        int ar  = idx >> 5;           // 32 float4 per row
        int ac  = (idx & 31) * 4;
        int grow = row0 + ar;
        float4 v = make_float4(0, 0, 0, 0);
        if (grow < M) v = *(const float4*)(A + (size_t)grow * lda + ac);
        *(float4*)(at + ar * 128 + ac) = v;
    }
    __syncthreads();
    int rg = tid >> 5;   // 0..7 → rows rg*4 .. rg*4+3
    int cg = tid & 31;   // cols cg*4 .. cg*4+3
    float4 acc[4] = {};
#pragma unroll 4
    for (int k = 0; k < 128; ++k) {
        float4 wv = *(const float4*)(wt + k * 128 + cg * 4);
#pragma unroll
        for (int i = 0; i < 4; ++i) {
            float a = at[(rg * 4 + i) * 128 + k];
            acc[i].x += a * wv.x; acc[i].y += a * wv.y;
            acc[i].z += a * wv.z; acc[i].w += a * wv.w;
        }
    }
#pragma unroll
    for (int i = 0; i < 4; ++i) {
        int grow = row0 + rg * 4 + i;
        if (grow < M) *(float4*)(out + (size_t)grow * 128 + cg * 4) = acc[i];
    }
}

// ---------- fused aggregate + bias + relu + write out1 ----------
// one wave per node; lane handles 2 contiguous channels.
__global__ __launch_bounds__(256) void k_agg(const float* __restrict__ hW,
                                             const int* __restrict__ rowptr,
                                             const int* __restrict__ csr_src,
                                             const float* __restrict__ csr_norm,
                                             const float* __restrict__ dinv,
                                             const float* __restrict__ bias,
                                             float* __restrict__ out1,
                                             int N, int layer) {
    int wave = threadIdx.x >> 6;
    int lane = threadIdx.x & 63;
    int n = blockIdx.x * 4 + wave;
    if (n >= N) return;
    float din = dinv[n];
    float2 h0 = ((const float2*)(hW + (size_t)n * DIM))[lane];
    float ax = h0.x * din * din;   // self-loop contribution
    float ay = h0.y * din * din;
    int beg = rowptr[n], end = rowptr[n + 1];
    for (int base = beg; base < end; base += 64) {
        int cnt = min(64, end - base);
        int eidx = base + lane;
        int   smy = 0;
        float wmy = 0.0f;
        if (eidx < end) { smy = csr_src[eidx]; wmy = csr_norm[eidx]; }
        int j = 0;
        for (; j + 4 <= cnt; j += 4) {
            int   s0 = __shfl(smy, j),     s1 = __shfl(smy, j + 1);
            int   s2 = __shfl(smy, j + 2), s3 = __shfl(smy, j + 3);
            float w0 = __shfl(wmy, j),     w1 = __shfl(wmy, j + 1);
            float w2 = __shfl(wmy, j + 2), w3 = __shfl(wmy, j + 3);
            float2 v0 = ((const float2*)(hW + (size_t)s0 * DIM))[lane];
            float2 v1 = ((const float2*)(hW + (size_t)s1 * DIM))[lane];
            float2 v2 = ((const float2*)(hW + (size_t)s2 * DIM))[lane];
            float2 v3 = ((const float2*)(hW + (size_t)s3 * DIM))[lane];
            ax += w0 * v0.x + w1 * v1.x + w2 * v2.x + w3 * v3.x;
            ay += w0 * v0.y + w1 * v1.y + w2 * v2.y + w3 * v3.y;
        }
        for (; j < cnt; ++j) {
            int   ss = __shfl(smy, j);
            float ww = __shfl(wmy, j);
            float2 hv = ((const float2*)(hW + (size_t)ss * DIM))[lane];
            ax += ww * hv.x;
            ay += ww * hv.y;
        }
    }
    float2 b = ((const float2*)bias)[lane];
    float ox = fmaxf(ax + b.x, 0.0f);
    float oy = fmaxf(ay + b.y, 0.0f);
    size_t o1 = (size_t)n * OUT1_STRIDE + layer * DIM + lane * 2;
    *(float2*)(out1 + o1) = make_float2(ox, oy);
}

// ---------- mean-pool: one block per graph, 384 threads (one per channel) ----------
__global__ __launch_bounds__(384) void k_pool(const float* __restrict__ out1,
                                              const int* __restrict__ start,
                                              float* __restrict__ out0) {
    int g = blockIdx.x;
    int c = threadIdx.x;
    int beg = start[g], end = start[g + 1];
    float acc = 0.0f;
    int i = beg;
    for (; i + 4 <= end; i += 4) {
        float a0 = out1[(size_t)(i    ) * OUT1_STRIDE + c];
        float a1 = out1[(size_t)(i + 1) * OUT1_STRIDE + c];
        float a2 = out1[(size_t)(i + 2) * OUT1_STRIDE + c];
        float a3 = out1[(size_t)(i + 3) * OUT1_STRIDE + c];
        acc += a0 + a1 + a2 + a3;
    }
    for (; i < end; ++i) acc += out1[(size_t)i * OUT1_STRIDE + c];
    float cnt = (float)(end - beg);
    out0[(size_t)g * OUT1_STRIDE + c] = acc / fmaxf(cnt, 1.0f);
}

extern "C" void kernel_launch(void* const* d_in, const int* in_sizes, int n_in,
                              void* d_out, int out_size, void* d_ws, size_t ws_size,
                              hipStream_t stream) {
    const float* x     = (const float*)d_in[0];
    const int*   ei    = (const int*)d_in[1];
    const int*   batch = (const int*)d_in[2];
    const float* W0 = (const float*)d_in[3];
    const float* b0 = (const float*)d_in[4];
    const float* W1 = (const float*)d_in[5];
    const float* b1 = (const float*)d_in[6];
    const float* W2 = (const float*)d_in[7];
    const float* b2 = (const float*)d_in[8];
    (void)n_in; (void)ws_size; (void)out_size;

    const int E = in_sizes[1] / 2;
    const int N = in_sizes[2];
    const int* src = ei;
    const int* dst = ei + E;

    char* ws = (char*)d_ws;
    float* hW       = (float*)ws; ws += (size_t)NNODES * DIM * 4;
    float* dinv     = (float*)ws; ws += 50016 * 4;
    int*   rowcnt   = (int*)ws;   ws += 50016 * 4;
    int*   fillcnt  = (int*)ws;   ws += 50016 * 4;
    int*   rowptr   = (int*)ws;   ws += 50016 * 4;
    int*   csr_src  = (int*)ws;   ws += (size_t)NEDGES * 4;
    float* csr_norm = (float*)ws; ws += (size_t)NEDGES * 4;
    int*   gstart   = (int*)ws;   ws += 256 * 4;

    float* out0 = (float*)d_out;                 // [128, 384] pooled
    float* out1 = (float*)d_out + OUT0_ELEMS;    // [50000, 384] per-layer features

    hipMemsetAsync(rowcnt,  0, (size_t)N * 4, stream);
    hipMemsetAsync(fillcnt, 0, (size_t)N * 4, stream);

    k_count <<<(E + 255) / 256, 256, 0, stream>>>(dst, rowcnt, E);
    k_dinv  <<<(N + 255) / 256, 256, 0, stream>>>(rowcnt, dinv, N);
    k_scan  <<<1, 1024, 0, stream>>>(rowcnt, rowptr, N);
    k_fill  <<<(E + 255) / 256, 256, 0, stream>>>(src, dst, rowptr, fillcnt, dinv,
                                                  csr_src, csr_norm, E);
    k_bounds<<<1, 256, 0, stream>>>(batch, gstart, N);

    const float* Ws[3] = {W0, W1, W2};
    const float* bs[3] = {b0, b1, b2};
    for (int l = 0; l < 3; ++l) {
        const float* Ain = (l == 0) ? x : (out1 + (size_t)(l - 1) * DIM);
        int lda          = (l == 0) ? DIM : OUT1_STRIDE;
        k_gemm<<<(N + 31) / 32, 256, 0, stream>>>(Ain, lda, Ws[l], hW, N);
        k_agg <<<(N + 3) / 4, 256, 0, stream>>>(hW, rowptr, csr_src, csr_norm, dinv,
                                                bs[l], out1, N, l);
    }
    k_pool<<<NGRAPHS, 384, 0, stream>>>(out1, gstart, out0);
}

// Round 4
// 511.540 us; speedup vs baseline: 2.0874x; 1.1314x over previous
//
#include <hip/hip_runtime.h>

#define NNODES 50000
#define NEDGES 800000
#define DIM 128
#define NGRAPHS 128
#define OUT1_STRIDE 384   // 3 layers * 128 concat along axis 1
#define OUT0_ELEMS (NGRAPHS * OUT1_STRIDE)
#define SCAN_CHUNK 512

// ---------- CSR build ----------
__global__ void k_count(const int* __restrict__ dst, int* __restrict__ rowcnt, int E) {
    int e = blockIdx.x * blockDim.x + threadIdx.x;
    if (e < E) atomicAdd(&rowcnt[dst[e]], 1);
}

__global__ void k_dinv(const int* __restrict__ rowcnt, float* __restrict__ dinv, int N) {
    int i = blockIdx.x * blockDim.x + threadIdx.x;
    if (i < N) dinv[i] = rsqrtf((float)rowcnt[i] + 1.0f);  // +1 for self-loop
}

// ---------- hierarchical exclusive scan ----------
// phase 1: per-block (512-elem chunk) sum
__global__ __launch_bounds__(512) void k_sum(const int* __restrict__ cnt,
                                             int* __restrict__ bsum, int n) {
    __shared__ int red[512];
    int t = threadIdx.x;
    int i = blockIdx.x * SCAN_CHUNK + t;
    red[t] = (i < n) ? cnt[i] : 0;
    __syncthreads();
    for (int off = 256; off > 0; off >>= 1) {
        if (t < off) red[t] += red[t + off];
        __syncthreads();
    }
    if (t == 0) bsum[blockIdx.x] = red[0];
}

// phase 2: single block exclusive scan of block sums (nb <= 128)
__global__ __launch_bounds__(128) void k_scanb(const int* __restrict__ bsum,
                                               int* __restrict__ boff, int nb) {
    __shared__ int s[128];
    int t = threadIdx.x;
    int v = (t < nb) ? bsum[t] : 0;
    s[t] = v;
    __syncthreads();
    for (int off = 1; off < 128; off <<= 1) {
        int u = (t >= off) ? s[t - off] : 0;
        __syncthreads();
        s[t] += u;
        __syncthreads();
    }
    boff[t] = s[t] - v;  // exclusive
    if (t == nb - 1) boff[nb] = s[t];  // total
}

// phase 3: per-chunk exclusive scan + block offset -> rowptr
__global__ __launch_bounds__(512) void k_writeptr(const int* __restrict__ cnt,
                                                  const int* __restrict__ boff,
                                                  int* __restrict__ rowptr, int n) {
    __shared__ int s[512];
    int t = threadIdx.x;
    int i = blockIdx.x * SCAN_CHUNK + t;
    int v = (i < n) ? cnt[i] : 0;
    s[t] = v;
    __syncthreads();
    for (int off = 1; off < 512; off <<= 1) {
        int u = (t >= off) ? s[t - off] : 0;
        __syncthreads();
        s[t] += u;
        __syncthreads();
    }
    if (i < n) rowptr[i] = boff[blockIdx.x] + s[t] - v;
    if (i == n - 1) rowptr[n] = boff[blockIdx.x] + s[t];
}

__global__ void k_fill(const int* __restrict__ src, const int* __restrict__ dst,
                       const int* __restrict__ rowptr, int* __restrict__ fillcnt,
                       const float* __restrict__ dinv,
                       int* __restrict__ csr_src, float* __restrict__ csr_norm, int E) {
    int e = blockIdx.x * blockDim.x + threadIdx.x;
    if (e < E) {
        int d = dst[e], s = src[e];
        int pos = rowptr[d] + atomicAdd(&fillcnt[d], 1);
        csr_src[pos]  = s;
        csr_norm[pos] = dinv[s] * dinv[d];
    }
}

// batch is sorted: start[g] = first index with batch[i] >= g, start[NGRAPHS] = N
__global__ void k_bounds(const int* __restrict__ batch, int* __restrict__ start, int N) {
    int g = threadIdx.x;
    if (g > NGRAPHS) return;
    if (g == NGRAPHS) { start[g] = N; return; }
    int lo = 0, hi = N;
    while (lo < hi) {
        int mid = (lo + hi) >> 1;
        if (batch[mid] < g) lo = mid + 1; else hi = mid;
    }
    start[g] = lo;
}

// ---------- GEMM: out[M x 128] = A[M x 128, row stride lda] @ W[128 x 128] ----------
// 32 rows per block; full W (64 KB) staged in LDS once per block.
__global__ __launch_bounds__(256) void k_gemm(const float* __restrict__ A, int lda,
                                              const float* __restrict__ W,
                                              float* __restrict__ out, int M) {
    __shared__ float wt[128 * 128];  // 64 KB
    __shared__ float at[32 * 128];   // 16 KB
    int tid = threadIdx.x;
    int row0 = blockIdx.x * 32;
#pragma unroll
    for (int i = 0; i < 16; ++i)
        ((float4*)wt)[i * 256 + tid] = ((const float4*)W)[i * 256 + tid];
#pragma unroll
    for (int i = 0; i < 4; ++i) {
        int idx = i * 256 + tid;      // float4 index
        int ar  = idx >> 5;           // 32 float4 per row
        int ac  = (idx & 31) * 4;
        int grow = row0 + ar;
        float4 v = make_float4(0, 0, 0, 0);
        if (grow < M) v = *(const float4*)(A + (size_t)grow * lda + ac);
        *(float4*)(at + ar * 128 + ac) = v;
    }
    __syncthreads();
    int rg = tid >> 5;   // 0..7 → rows rg*4 .. rg*4+3
    int cg = tid & 31;   // cols cg*4 .. cg*4+3
    float4 acc[4] = {};
#pragma unroll 4
    for (int k = 0; k < 128; ++k) {
        float4 wv = *(const float4*)(wt + k * 128 + cg * 4);
#pragma unroll
        for (int i = 0; i < 4; ++i) {
            float a = at[(rg * 4 + i) * 128 + k];
            acc[i].x += a * wv.x; acc[i].y += a * wv.y;
            acc[i].z += a * wv.z; acc[i].w += a * wv.w;
        }
    }
#pragma unroll
    for (int i = 0; i < 4; ++i) {
        int grow = row0 + rg * 4 + i;
        if (grow < M) *(float4*)(out + (size_t)grow * 128 + cg * 4) = acc[i];
    }
}

// ---------- fused aggregate + bias + relu + write out1 ----------
// one wave per node; lane handles 2 contiguous channels.
__global__ __launch_bounds__(256) void k_agg(const float* __restrict__ hW,
                                             const int* __restrict__ rowptr,
                                             const int* __restrict__ csr_src,
                                             const float* __restrict__ csr_norm,
                                             const float* __restrict__ dinv,
                                             const float* __restrict__ bias,
                                             float* __restrict__ out1,
                                             int N, int layer) {
    int wave = threadIdx.x >> 6;
    int lane = threadIdx.x & 63;
    int n = blockIdx.x * 4 + wave;
    if (n >= N) return;
    float din = dinv[n];
    float2 h0 = ((const float2*)(hW + (size_t)n * DIM))[lane];
    float ax = h0.x * din * din;   // self-loop contribution
    float ay = h0.y * din * din;
    int beg = rowptr[n], end = rowptr[n + 1];
    for (int base = beg; base < end; base += 64) {
        int cnt = min(64, end - base);
        int eidx = base + lane;
        int   smy = 0;
        float wmy = 0.0f;
        if (eidx < end) { smy = csr_src[eidx]; wmy = csr_norm[eidx]; }
        int j = 0;
        for (; j + 4 <= cnt; j += 4) {
            int   s0 = __shfl(smy, j),     s1 = __shfl(smy, j + 1);
            int   s2 = __shfl(smy, j + 2), s3 = __shfl(smy, j + 3);
            float w0 = __shfl(wmy, j),     w1 = __shfl(wmy, j + 1);
            float w2 = __shfl(wmy, j + 2), w3 = __shfl(wmy, j + 3);
            float2 v0 = ((const float2*)(hW + (size_t)s0 * DIM))[lane];
            float2 v1 = ((const float2*)(hW + (size_t)s1 * DIM))[lane];
            float2 v2 = ((const float2*)(hW + (size_t)s2 * DIM))[lane];
            float2 v3 = ((const float2*)(hW + (size_t)s3 * DIM))[lane];
            ax += w0 * v0.x + w1 * v1.x + w2 * v2.x + w3 * v3.x;
            ay += w0 * v0.y + w1 * v1.y + w2 * v2.y + w3 * v3.y;
        }
        for (; j < cnt; ++j) {
            int   ss = __shfl(smy, j);
            float ww = __shfl(wmy, j);
            float2 hv = ((const float2*)(hW + (size_t)ss * DIM))[lane];
            ax += ww * hv.x;
            ay += ww * hv.y;
        }
    }
    float2 b = ((const float2*)bias)[lane];
    float ox = fmaxf(ax + b.x, 0.0f);
    float oy = fmaxf(ay + b.y, 0.0f);
    size_t o1 = (size_t)n * OUT1_STRIDE + layer * DIM + lane * 2;
    *(float2*)(out1 + o1) = make_float2(ox, oy);
}

// ---------- mean-pool: one block per graph, 384 threads (one per channel) ----------
__global__ __launch_bounds__(384) void k_pool(const float* __restrict__ out1,
                                              const int* __restrict__ start,
                                              float* __restrict__ out0) {
    int g = blockIdx.x;
    int c = threadIdx.x;
    int beg = start[g], end = start[g + 1];
    float acc = 0.0f;
    int i = beg;
    for (; i + 4 <= end; i += 4) {
        float a0 = out1[(size_t)(i    ) * OUT1_STRIDE + c];
        float a1 = out1[(size_t)(i + 1) * OUT1_STRIDE + c];
        float a2 = out1[(size_t)(i + 2) * OUT1_STRIDE + c];
        float a3 = out1[(size_t)(i + 3) * OUT1_STRIDE + c];
        acc += a0 + a1 + a2 + a3;
    }
    for (; i < end; ++i) acc += out1[(size_t)i * OUT1_STRIDE + c];
    float cnt = (float)(end - beg);
    out0[(size_t)g * OUT1_STRIDE + c] = acc / fmaxf(cnt, 1.0f);
}

extern "C" void kernel_launch(void* const* d_in, const int* in_sizes, int n_in,
                              void* d_out, int out_size, void* d_ws, size_t ws_size,
                              hipStream_t stream) {
    const float* x     = (const float*)d_in[0];
    const int*   ei    = (const int*)d_in[1];
    const int*   batch = (const int*)d_in[2];
    const float* W0 = (const float*)d_in[3];
    const float* b0 = (const float*)d_in[4];
    const float* W1 = (const float*)d_in[5];
    const float* b1 = (const float*)d_in[6];
    const float* W2 = (const float*)d_in[7];
    const float* b2 = (const float*)d_in[8];
    (void)n_in; (void)ws_size; (void)out_size;

    const int E = in_sizes[1] / 2;
    const int N = in_sizes[2];
    const int* src = ei;
    const int* dst = ei + E;

    char* ws = (char*)d_ws;
    float* hW       = (float*)ws; ws += (size_t)NNODES * DIM * 4;
    float* dinv     = (float*)ws; ws += 50016 * 4;
    int*   rowcnt   = (int*)ws;   ws += 50016 * 4;
    int*   fillcnt  = (int*)ws;   ws += 50016 * 4;
    int*   rowptr   = (int*)ws;   ws += 50016 * 4;
    int*   csr_src  = (int*)ws;   ws += (size_t)NEDGES * 4;
    float* csr_norm = (float*)ws; ws += (size_t)NEDGES * 4;
    int*   gstart   = (int*)ws;   ws += 256 * 4;
    int*   bsum     = (int*)ws;   ws += 256 * 4;
    int*   boff     = (int*)ws;   ws += 256 * 4;

    float* out0 = (float*)d_out;                 // [128, 384] pooled
    float* out1 = (float*)d_out + OUT0_ELEMS;    // [50000, 384] per-layer features

    const int nb = (N + SCAN_CHUNK - 1) / SCAN_CHUNK;  // 98 for N=50000

    hipMemsetAsync(rowcnt,  0, (size_t)N * 4, stream);
    hipMemsetAsync(fillcnt, 0, (size_t)N * 4, stream);

    k_count   <<<(E + 255) / 256, 256, 0, stream>>>(dst, rowcnt, E);
    k_dinv    <<<(N + 255) / 256, 256, 0, stream>>>(rowcnt, dinv, N);
    k_sum     <<<nb, 512, 0, stream>>>(rowcnt, bsum, N);
    k_scanb   <<<1, 128, 0, stream>>>(bsum, boff, nb);
    k_writeptr<<<nb, 512, 0, stream>>>(rowcnt, boff, rowptr, N);
    k_fill    <<<(E + 255) / 256, 256, 0, stream>>>(src, dst, rowptr, fillcnt, dinv,
                                                    csr_src, csr_norm, E);
    k_bounds  <<<1, 256, 0, stream>>>(batch, gstart, N);

    const float* Ws[3] = {W0, W1, W2};
    const float* bs[3] = {b0, b1, b2};
    for (int l = 0; l < 3; ++l) {
        const float* Ain = (l == 0) ? x : (out1 + (size_t)(l - 1) * DIM);
        int lda          = (l == 0) ? DIM : OUT1_STRIDE;
        k_gemm<<<(N + 31) / 32, 256, 0, stream>>>(Ain, lda, Ws[l], hW, N);
        k_agg <<<(N + 3) / 4, 256, 0, stream>>>(hW, rowptr, csr_src, csr_norm, dinv,
                                                bs[l], out1, N, l);
    }
    k_pool<<<NGRAPHS, 384, 0, stream>>>(out1, gstart, out0);
}

// Round 5
// 417.652 us; speedup vs baseline: 2.5567x; 1.2248x over previous
//
#include <hip/hip_runtime.h>

#define NNODES 50000
#define NEDGES 800000
#define DIM 128
#define NGRAPHS 128
#define OUT1_STRIDE 384   // 3 layers * 128 concat along axis 1
#define OUT0_ELEMS (NGRAPHS * OUT1_STRIDE)
#define SCAN_CHUNK 512

typedef unsigned int uint;

__device__ inline uint rne_bf16(float f) {
    uint b = __float_as_uint(f);
    return (b + 0x7fffu + ((b >> 16) & 1u)) >> 16;
}
__device__ inline uint pack_bf16(float lo, float hi) {
    return rne_bf16(lo) | (rne_bf16(hi) << 16);
}

// ---------- CSR build ----------
// count in-degree AND record each edge's rank within its destination row
__global__ void k_count(const int* __restrict__ dst, int* __restrict__ rowcnt,
                        int* __restrict__ rank, int E) {
    int e = blockIdx.x * blockDim.x + threadIdx.x;
    if (e < E) rank[e] = atomicAdd(&rowcnt[dst[e]], 1);
}

__global__ void k_dinv(const int* __restrict__ rowcnt, float* __restrict__ dinv, int N) {
    int i = blockIdx.x * blockDim.x + threadIdx.x;
    if (i < N) dinv[i] = rsqrtf((float)rowcnt[i] + 1.0f);  // +1 for self-loop
}

// ---------- hierarchical exclusive scan ----------
__global__ __launch_bounds__(512) void k_sum(const int* __restrict__ cnt,
                                             int* __restrict__ bsum, int n) {
    __shared__ int red[512];
    int t = threadIdx.x;
    int i = blockIdx.x * SCAN_CHUNK + t;
    red[t] = (i < n) ? cnt[i] : 0;
    __syncthreads();
    for (int off = 256; off > 0; off >>= 1) {
        if (t < off) red[t] += red[t + off];
        __syncthreads();
    }
    if (t == 0) bsum[blockIdx.x] = red[0];
}

__global__ __launch_bounds__(128) void k_scanb(const int* __restrict__ bsum,
                                               int* __restrict__ boff, int nb) {
    __shared__ int s[128];
    int t = threadIdx.x;
    int v = (t < nb) ? bsum[t] : 0;
    s[t] = v;
    __syncthreads();
    for (int off = 1; off < 128; off <<= 1) {
        int u = (t >= off) ? s[t - off] : 0;
        __syncthreads();
        s[t] += u;
        __syncthreads();
    }
    boff[t] = s[t] - v;  // exclusive
    if (t == nb - 1) boff[nb] = s[t];
}

__global__ __launch_bounds__(512) void k_writeptr(const int* __restrict__ cnt,
                                                  const int* __restrict__ boff,
                                                  int* __restrict__ rowptr, int n) {
    __shared__ int s[512];
    int t = threadIdx.x;
    int i = blockIdx.x * SCAN_CHUNK + t;
    int v = (i < n) ? cnt[i] : 0;
    s[t] = v;
    __syncthreads();
    for (int off = 1; off < 512; off <<= 1) {
        int u = (t >= off) ? s[t - off] : 0;
        __syncthreads();
        s[t] += u;
        __syncthreads();
    }
    if (i < n) rowptr[i] = boff[blockIdx.x] + s[t] - v;
    if (i == n - 1) rowptr[n] = boff[blockIdx.x] + s[t];
}

// atomic-free fill: pos = rowptr[dst] + rank; single 8B interleaved scatter
__global__ void k_fill(const int* __restrict__ src, const int* __restrict__ dst,
                       const int* __restrict__ rowptr, const int* __restrict__ rank,
                       const float* __restrict__ dinv,
                       int2* __restrict__ csr, int E) {
    int e = blockIdx.x * blockDim.x + threadIdx.x;
    if (e < E) {
        int d = dst[e], s = src[e];
        int pos = rowptr[d] + rank[e];
        csr[pos] = make_int2(s, __float_as_int(dinv[s] * dinv[d]));
    }
}

// batch is sorted: start[g] = first index with batch[i] >= g
__global__ void k_bounds(const int* __restrict__ batch, int* __restrict__ start, int N) {
    int g = threadIdx.x;
    if (g > NGRAPHS) return;
    if (g == NGRAPHS) { start[g] = N; return; }
    int lo = 0, hi = N;
    while (lo < hi) {
        int mid = (lo + hi) >> 1;
        if (batch[mid] < g) lo = mid + 1; else hi = mid;
    }
    start[g] = lo;
}

// ---------- GEMM: hb[M x 128 bf16] = A[M x 128 f32, stride lda] @ W[128 x 128] ----------
__global__ __launch_bounds__(256) void k_gemm(const float* __restrict__ A, int lda,
                                              const float* __restrict__ W,
                                              uint* __restrict__ hb, int M) {
    __shared__ float wt[128 * 128];  // 64 KB
    __shared__ float at[32 * 128];   // 16 KB
    int tid = threadIdx.x;
    int row0 = blockIdx.x * 32;
#pragma unroll
    for (int i = 0; i < 16; ++i)
        ((float4*)wt)[i * 256 + tid] = ((const float4*)W)[i * 256 + tid];
#pragma unroll
    for (int i = 0; i < 4; ++i) {
        int idx = i * 256 + tid;      // float4 index
        int ar  = idx >> 5;           // 32 float4 per row
        int ac  = (idx & 31) * 4;
        int grow = row0 + ar;
        float4 v = make_float4(0, 0, 0, 0);
        if (grow < M) v = *(const float4*)(A + (size_t)grow * lda + ac);
        *(float4*)(at + ar * 128 + ac) = v;
    }
    __syncthreads();
    int rg = tid >> 5;   // rows rg*4 .. rg*4+3
    int cg = tid & 31;   // cols cg*4 .. cg*4+3
    float4 acc[4] = {};
#pragma unroll 4
    for (int k = 0; k < 128; ++k) {
        float4 wv = *(const float4*)(wt + k * 128 + cg * 4);
#pragma unroll
        for (int i = 0; i < 4; ++i) {
            float a = at[(rg * 4 + i) * 128 + k];
            acc[i].x += a * wv.x; acc[i].y += a * wv.y;
            acc[i].z += a * wv.z; acc[i].w += a * wv.w;
        }
    }
#pragma unroll
    for (int i = 0; i < 4; ++i) {
        int grow = row0 + rg * 4 + i;
        if (grow < M) {
            uint2 pk;
            pk.x = pack_bf16(acc[i].x, acc[i].y);
            pk.y = pack_bf16(acc[i].z, acc[i].w);
            *(uint2*)(hb + (size_t)grow * 64 + cg * 2) = pk;  // 64 uints per row
        }
    }
}

// ---------- fused aggregate + bias + relu + write out1 ----------
// one wave per node; lane handles channels (2*lane, 2*lane+1) packed in one uint
__global__ __launch_bounds__(256) void k_agg(const uint* __restrict__ hb,
                                             const int* __restrict__ rowptr,
                                             const int2* __restrict__ csr,
                                             const float* __restrict__ dinv,
                                             const float* __restrict__ bias,
                                             float* __restrict__ out1,
                                             int N, int layer) {
    int wave = threadIdx.x >> 6;
    int lane = threadIdx.x & 63;
    int n = blockIdx.x * 4 + wave;
    if (n >= N) return;
    float din = dinv[n];
    uint u = hb[(size_t)n * 64 + lane];
    float ax = __uint_as_float(u << 16)          * din * din;  // self-loop
    float ay = __uint_as_float(u & 0xffff0000u)  * din * din;
    int beg = rowptr[n], end = rowptr[n + 1];
    for (int base = beg; base < end; base += 64) {
        int cnt = min(64, end - base);
        int eidx = base + lane;
        int   smy = 0;
        float wmy = 0.0f;
        if (eidx < end) { int2 p = csr[eidx]; smy = p.x; wmy = __int_as_float(p.y); }
        int j = 0;
        for (; j + 4 <= cnt; j += 4) {
            int   s0 = __shfl(smy, j),     s1 = __shfl(smy, j + 1);
            int   s2 = __shfl(smy, j + 2), s3 = __shfl(smy, j + 3);
            float w0 = __shfl(wmy, j),     w1 = __shfl(wmy, j + 1);
            float w2 = __shfl(wmy, j + 2), w3 = __shfl(wmy, j + 3);
            uint u0 = hb[(size_t)s0 * 64 + lane];
            uint u1 = hb[(size_t)s1 * 64 + lane];
            uint u2 = hb[(size_t)s2 * 64 + lane];
            uint u3 = hb[(size_t)s3 * 64 + lane];
            ax += w0 * __uint_as_float(u0 << 16) + w1 * __uint_as_float(u1 << 16)
                + w2 * __uint_as_float(u2 << 16) + w3 * __uint_as_float(u3 << 16);
            ay += w0 * __uint_as_float(u0 & 0xffff0000u) + w1 * __uint_as_float(u1 & 0xffff0000u)
                + w2 * __uint_as_float(u2 & 0xffff0000u) + w3 * __uint_as_float(u3 & 0xffff0000u);
        }
        for (; j < cnt; ++j) {
            int   ss = __shfl(smy, j);
            float ww = __shfl(wmy, j);
            uint uu = hb[(size_t)ss * 64 + lane];
            ax += ww * __uint_as_float(uu << 16);
            ay += ww * __uint_as_float(uu & 0xffff0000u);
        }
    }
    float2 b = ((const float2*)bias)[lane];
    float ox = fmaxf(ax + b.x, 0.0f);
    float oy = fmaxf(ay + b.y, 0.0f);
    size_t o1 = (size_t)n * OUT1_STRIDE + layer * DIM + lane * 2;
    *(float2*)(out1 + o1) = make_float2(ox, oy);
}

// ---------- mean-pool: one block per graph, 384 threads (one per channel) ----------
__global__ __launch_bounds__(384) void k_pool(const float* __restrict__ out1,
                                              const int* __restrict__ start,
                                              float* __restrict__ out0) {
    int g = blockIdx.x;
    int c = threadIdx.x;
    int beg = start[g], end = start[g + 1];
    float acc = 0.0f;
    int i = beg;
    for (; i + 4 <= end; i += 4) {
        float a0 = out1[(size_t)(i    ) * OUT1_STRIDE + c];
        float a1 = out1[(size_t)(i + 1) * OUT1_STRIDE + c];
        float a2 = out1[(size_t)(i + 2) * OUT1_STRIDE + c];
        float a3 = out1[(size_t)(i + 3) * OUT1_STRIDE + c];
        acc += a0 + a1 + a2 + a3;
    }
    for (; i < end; ++i) acc += out1[(size_t)i * OUT1_STRIDE + c];
    float cnt = (float)(end - beg);
    out0[(size_t)g * OUT1_STRIDE + c] = acc / fmaxf(cnt, 1.0f);
}

extern "C" void kernel_launch(void* const* d_in, const int* in_sizes, int n_in,
                              void* d_out, int out_size, void* d_ws, size_t ws_size,
                              hipStream_t stream) {
    const float* x     = (const float*)d_in[0];
    const int*   ei    = (const int*)d_in[1];
    const int*   batch = (const int*)d_in[2];
    const float* W0 = (const float*)d_in[3];
    const float* b0 = (const float*)d_in[4];
    const float* W1 = (const float*)d_in[5];
    const float* b1 = (const float*)d_in[6];
    const float* W2 = (const float*)d_in[7];
    const float* b2 = (const float*)d_in[8];
    (void)n_in; (void)ws_size; (void)out_size;

    const int E = in_sizes[1] / 2;
    const int N = in_sizes[2];
    const int* src = ei;
    const int* dst = ei + E;

    char* ws = (char*)d_ws;
    uint*  hb       = (uint*)ws;  ws += (size_t)NNODES * 64 * 4;   // bf16 h@W, packed
    float* dinv     = (float*)ws; ws += 50016 * 4;
    int*   rowcnt   = (int*)ws;   ws += 50016 * 4;
    int*   rowptr   = (int*)ws;   ws += 50016 * 4;
    int*   rank     = (int*)ws;   ws += (size_t)NEDGES * 4;
    int2*  csr      = (int2*)ws;  ws += (size_t)NEDGES * 8;
    int*   gstart   = (int*)ws;   ws += 256 * 4;
    int*   bsum     = (int*)ws;   ws += 256 * 4;
    int*   boff     = (int*)ws;   ws += 256 * 4;

    float* out0 = (float*)d_out;                 // [128, 384] pooled
    float* out1 = (float*)d_out + OUT0_ELEMS;    // [50000, 384] per-layer features

    const int nb = (N + SCAN_CHUNK - 1) / SCAN_CHUNK;  // 98 for N=50000

    hipMemsetAsync(rowcnt, 0, (size_t)N * 4, stream);

    k_count   <<<(E + 255) / 256, 256, 0, stream>>>(dst, rowcnt, rank, E);
    k_dinv    <<<(N + 255) / 256, 256, 0, stream>>>(rowcnt, dinv, N);
    k_sum     <<<nb, 512, 0, stream>>>(rowcnt, bsum, N);
    k_scanb   <<<1, 128, 0, stream>>>(bsum, boff, nb);
    k_writeptr<<<nb, 512, 0, stream>>>(rowcnt, boff, rowptr, N);
    k_fill    <<<(E + 255) / 256, 256, 0, stream>>>(src, dst, rowptr, rank, dinv,
                                                    csr, E);
    k_bounds  <<<1, 256, 0, stream>>>(batch, gstart, N);

    const float* Ws[3] = {W0, W1, W2};
    const float* bs[3] = {b0, b1, b2};
    for (int l = 0; l < 3; ++l) {
        const float* Ain = (l == 0) ? x : (out1 + (size_t)(l - 1) * DIM);
        int lda          = (l == 0) ? DIM : OUT1_STRIDE;
        k_gemm<<<(N + 31) / 32, 256, 0, stream>>>(Ain, lda, Ws[l], hb, N);
        k_agg <<<(N + 3) / 4, 256, 0, stream>>>(hb, rowptr, csr, dinv,
                                                bs[l], out1, N, l);
    }
    k_pool<<<NGRAPHS, 384, 0, stream>>>(out1, gstart, out0);
}

// Round 6
// 406.221 us; speedup vs baseline: 2.6286x; 1.0281x over previous
//
#include <hip/hip_runtime.h>

#define NNODES 50000
#define NEDGES 800000
#define DIM 128
#define NGRAPHS 128
#define OUT1_STRIDE 384   // 3 layers * 128 concat along axis 1
#define OUT0_ELEMS (NGRAPHS * OUT1_STRIDE)
#define SCAN_CHUNK 512

typedef unsigned int uint;

__device__ inline uint rne_bf16(float f) {
    uint b = __float_as_uint(f);
    return (b + 0x7fffu + ((b >> 16) & 1u)) >> 16;
}
__device__ inline uint pack_bf16(float lo, float hi) {
    return rne_bf16(lo) | (rne_bf16(hi) << 16);
}

// ---------- CSR build ----------
// count in-degree AND record each edge's rank within its destination row
__global__ void k_count(const int* __restrict__ dst, int* __restrict__ rowcnt,
                        int* __restrict__ rank, int E) {
    int e = blockIdx.x * blockDim.x + threadIdx.x;
    if (e < E) rank[e] = atomicAdd(&rowcnt[dst[e]], 1);
}

__global__ void k_dinv(const int* __restrict__ rowcnt, float* __restrict__ dinv, int N) {
    int i = blockIdx.x * blockDim.x + threadIdx.x;
    if (i < N) dinv[i] = rsqrtf((float)rowcnt[i] + 1.0f);  // +1 for self-loop
}

// ---------- hierarchical exclusive scan ----------
__global__ __launch_bounds__(512) void k_sum(const int* __restrict__ cnt,
                                             int* __restrict__ bsum, int n) {
    __shared__ int red[512];
    int t = threadIdx.x;
    int i = blockIdx.x * SCAN_CHUNK + t;
    red[t] = (i < n) ? cnt[i] : 0;
    __syncthreads();
    for (int off = 256; off > 0; off >>= 1) {
        if (t < off) red[t] += red[t + off];
        __syncthreads();
    }
    if (t == 0) bsum[blockIdx.x] = red[0];
}

__global__ __launch_bounds__(128) void k_scanb(const int* __restrict__ bsum,
                                               int* __restrict__ boff, int nb) {
    __shared__ int s[128];
    int t = threadIdx.x;
    int v = (t < nb) ? bsum[t] : 0;
    s[t] = v;
    __syncthreads();
    for (int off = 1; off < 128; off <<= 1) {
        int u = (t >= off) ? s[t - off] : 0;
        __syncthreads();
        s[t] += u;
        __syncthreads();
    }
    boff[t] = s[t] - v;  // exclusive
    if (t == nb - 1) boff[nb] = s[t];
}

__global__ __launch_bounds__(512) void k_writeptr(const int* __restrict__ cnt,
                                                  const int* __restrict__ boff,
                                                  int* __restrict__ rowptr, int n) {
    __shared__ int s[512];
    int t = threadIdx.x;
    int i = blockIdx.x * SCAN_CHUNK + t;
    int v = (i < n) ? cnt[i] : 0;
    s[t] = v;
    __syncthreads();
    for (int off = 1; off < 512; off <<= 1) {
        int u = (t >= off) ? s[t - off] : 0;
        __syncthreads();
        s[t] += u;
        __syncthreads();
    }
    if (i < n) rowptr[i] = boff[blockIdx.x] + s[t] - v;
    if (i == n - 1) rowptr[n] = boff[blockIdx.x] + s[t];
}

// atomic-free fill: pos = rowptr[dst] + rank; 4B scatter (src only; norm folded out)
__global__ void k_fill(const int* __restrict__ src, const int* __restrict__ dst,
                       const int* __restrict__ rowptr, const int* __restrict__ rank,
                       int* __restrict__ csr_src, int E) {
    int e = blockIdx.x * blockDim.x + threadIdx.x;
    if (e < E) {
        int d = dst[e];
        csr_src[rowptr[d] + rank[e]] = src[e];
    }
}

// batch is sorted: start[g] = first index with batch[i] >= g
__global__ void k_bounds(const int* __restrict__ batch, int* __restrict__ start, int N) {
    int g = threadIdx.x;
    if (g > NGRAPHS) return;
    if (g == NGRAPHS) { start[g] = N; return; }
    int lo = 0, hi = N;
    while (lo < hi) {
        int mid = (lo + hi) >> 1;
        if (batch[mid] < g) lo = mid + 1; else hi = mid;
    }
    start[g] = lo;
}

// ---------- GEMM: hb[M x 128 bf16] = A[M x 128 f32, stride lda] @ W[128 x 128] ----------
// k-blocked by 4: A fragments loaded as float4 (ds_read_b128), VALU-bound inner loop.
__global__ __launch_bounds__(256) void k_gemm(const float* __restrict__ A, int lda,
                                              const float* __restrict__ W,
                                              uint* __restrict__ hb, int M) {
    __shared__ float wt[128 * 128];  // 64 KB
    __shared__ float at[32 * 128];   // 16 KB
    int tid = threadIdx.x;
    int row0 = blockIdx.x * 32;
#pragma unroll
    for (int i = 0; i < 16; ++i)
        ((float4*)wt)[i * 256 + tid] = ((const float4*)W)[i * 256 + tid];
#pragma unroll
    for (int i = 0; i < 4; ++i) {
        int idx = i * 256 + tid;      // float4 index
        int ar  = idx >> 5;           // 32 float4 per row
        int ac  = (idx & 31) * 4;
        int grow = row0 + ar;
        float4 v = make_float4(0, 0, 0, 0);
        if (grow < M) v = *(const float4*)(A + (size_t)grow * lda + ac);
        *(float4*)(at + ar * 128 + ac) = v;
    }
    __syncthreads();
    int rg = tid >> 5;   // rows rg*4 .. rg*4+3
    int cg = tid & 31;   // cols cg*4 .. cg*4+3
    float4 acc[4] = {};
#pragma unroll 2
    for (int k4 = 0; k4 < 32; ++k4) {
        float av[4][4];
#pragma unroll
        for (int i = 0; i < 4; ++i) {
            float4 t = *(const float4*)(at + (rg * 4 + i) * 128 + k4 * 4);
            av[i][0] = t.x; av[i][1] = t.y; av[i][2] = t.z; av[i][3] = t.w;
        }
#pragma unroll
        for (int kk = 0; kk < 4; ++kk) {
            float4 wv = *(const float4*)(wt + (k4 * 4 + kk) * 128 + cg * 4);
#pragma unroll
            for (int i = 0; i < 4; ++i) {
                float a = av[i][kk];
                acc[i].x += a * wv.x; acc[i].y += a * wv.y;
                acc[i].z += a * wv.z; acc[i].w += a * wv.w;
            }
        }
    }
#pragma unroll
    for (int i = 0; i < 4; ++i) {
        int grow = row0 + rg * 4 + i;
        if (grow < M) {
            uint2 pk;
            pk.x = pack_bf16(acc[i].x, acc[i].y);
            pk.y = pack_bf16(acc[i].z, acc[i].w);
            *(uint2*)(hb + (size_t)grow * 64 + cg * 2) = pk;  // 64 uints per row
        }
    }
}

// ---------- fused aggregate + bias + relu + write out1 ----------
// one wave per node; lane handles channels (2*lane, 2*lane+1) packed in one uint.
// acc accumulates dinv[s]*h[s]; multiply by dinv[n] once at the end.
__global__ __launch_bounds__(256) void k_agg(const uint* __restrict__ hb,
                                             const int* __restrict__ rowptr,
                                             const int* __restrict__ csr_src,
                                             const float* __restrict__ dinv,
                                             const float* __restrict__ bias,
                                             float* __restrict__ out1,
                                             int N, int layer) {
    int wave = threadIdx.x >> 6;
    int lane = threadIdx.x & 63;
    int n = blockIdx.x * 4 + wave;
    if (n >= N) return;
    float din = dinv[n];
    uint u = hb[(size_t)n * 64 + lane];
    float ax = __uint_as_float(u << 16)         * din;  // self-loop (din^2 total)
    float ay = __uint_as_float(u & 0xffff0000u) * din;
    int beg = rowptr[n], end = rowptr[n + 1];
    for (int base = beg; base < end; base += 64) {
        int cnt = min(64, end - base);
        int eidx = base + lane;
        int   smy = 0;
        float wmy = 0.0f;
        if (eidx < end) { smy = csr_src[eidx]; wmy = dinv[smy]; }
        int j = 0;
        for (; j + 4 <= cnt; j += 4) {
            int   s0 = __shfl(smy, j),     s1 = __shfl(smy, j + 1);
            int   s2 = __shfl(smy, j + 2), s3 = __shfl(smy, j + 3);
            float w0 = __shfl(wmy, j),     w1 = __shfl(wmy, j + 1);
            float w2 = __shfl(wmy, j + 2), w3 = __shfl(wmy, j + 3);
            uint u0 = hb[(size_t)s0 * 64 + lane];
            uint u1 = hb[(size_t)s1 * 64 + lane];
            uint u2 = hb[(size_t)s2 * 64 + lane];
            uint u3 = hb[(size_t)s3 * 64 + lane];
            ax += w0 * __uint_as_float(u0 << 16) + w1 * __uint_as_float(u1 << 16)
                + w2 * __uint_as_float(u2 << 16) + w3 * __uint_as_float(u3 << 16);
            ay += w0 * __uint_as_float(u0 & 0xffff0000u) + w1 * __uint_as_float(u1 & 0xffff0000u)
                + w2 * __uint_as_float(u2 & 0xffff0000u) + w3 * __uint_as_float(u3 & 0xffff0000u);
        }
        for (; j < cnt; ++j) {
            int   ss = __shfl(smy, j);
            float ww = __shfl(wmy, j);
            uint uu = hb[(size_t)ss * 64 + lane];
            ax += ww * __uint_as_float(uu << 16);
            ay += ww * __uint_as_float(uu & 0xffff0000u);
        }
    }
    float2 b = ((const float2*)bias)[lane];
    float ox = fmaxf(din * ax + b.x, 0.0f);
    float oy = fmaxf(din * ay + b.y, 0.0f);
    size_t o1 = (size_t)n * OUT1_STRIDE + layer * DIM + lane * 2;
    *(float2*)(out1 + o1) = make_float2(ox, oy);
}

// ---------- mean-pool: one block per graph, 384 threads (one per channel) ----------
__global__ __launch_bounds__(384) void k_pool(const float* __restrict__ out1,
                                              const int* __restrict__ start,
                                              float* __restrict__ out0) {
    int g = blockIdx.x;
    int c = threadIdx.x;
    int beg = start[g], end = start[g + 1];
    float acc = 0.0f;
    int i = beg;
    for (; i + 4 <= end; i += 4) {
        float a0 = out1[(size_t)(i    ) * OUT1_STRIDE + c];
        float a1 = out1[(size_t)(i + 1) * OUT1_STRIDE + c];
        float a2 = out1[(size_t)(i + 2) * OUT1_STRIDE + c];
        float a3 = out1[(size_t)(i + 3) * OUT1_STRIDE + c];
        acc += a0 + a1 + a2 + a3;
    }
    for (; i < end; ++i) acc += out1[(size_t)i * OUT1_STRIDE + c];
    float cnt = (float)(end - beg);
    out0[(size_t)g * OUT1_STRIDE + c] = acc / fmaxf(cnt, 1.0f);
}

extern "C" void kernel_launch(void* const* d_in, const int* in_sizes, int n_in,
                              void* d_out, int out_size, void* d_ws, size_t ws_size,
                              hipStream_t stream) {
    const float* x     = (const float*)d_in[0];
    const int*   ei    = (const int*)d_in[1];
    const int*   batch = (const int*)d_in[2];
    const float* W0 = (const float*)d_in[3];
    const float* b0 = (const float*)d_in[4];
    const float* W1 = (const float*)d_in[5];
    const float* b1 = (const float*)d_in[6];
    const float* W2 = (const float*)d_in[7];
    const float* b2 = (const float*)d_in[8];
    (void)n_in; (void)ws_size; (void)out_size;

    const int E = in_sizes[1] / 2;
    const int N = in_sizes[2];
    const int* src = ei;
    const int* dst = ei + E;

    char* ws = (char*)d_ws;
    uint*  hb       = (uint*)ws;  ws += (size_t)NNODES * 64 * 4;   // bf16 h@W, packed
    float* dinv     = (float*)ws; ws += 50016 * 4;
    int*   rowcnt   = (int*)ws;   ws += 50016 * 4;
    int*   rowptr   = (int*)ws;   ws += 50016 * 4;
    int*   rank     = (int*)ws;   ws += (size_t)NEDGES * 4;
    int*   csr_src  = (int*)ws;   ws += (size_t)NEDGES * 4;
    int*   gstart   = (int*)ws;   ws += 256 * 4;
    int*   bsum     = (int*)ws;   ws += 256 * 4;
    int*   boff     = (int*)ws;   ws += 256 * 4;

    float* out0 = (float*)d_out;                 // [128, 384] pooled
    float* out1 = (float*)d_out + OUT0_ELEMS;    // [50000, 384] per-layer features

    const int nb = (N + SCAN_CHUNK - 1) / SCAN_CHUNK;  // 98 for N=50000

    hipMemsetAsync(rowcnt, 0, (size_t)N * 4, stream);

    k_count   <<<(E + 255) / 256, 256, 0, stream>>>(dst, rowcnt, rank, E);
    k_dinv    <<<(N + 255) / 256, 256, 0, stream>>>(rowcnt, dinv, N);
    k_sum     <<<nb, 512, 0, stream>>>(rowcnt, bsum, N);
    k_scanb   <<<1, 128, 0, stream>>>(bsum, boff, nb);
    k_writeptr<<<nb, 512, 0, stream>>>(rowcnt, boff, rowptr, N);
    k_fill    <<<(E + 255) / 256, 256, 0, stream>>>(src, dst, rowptr, rank, csr_src, E);
    k_bounds  <<<1, 256, 0, stream>>>(batch, gstart, N);

    const float* Ws[3] = {W0, W1, W2};
    const float* bs[3] = {b0, b1, b2};
    for (int l = 0; l < 3; ++l) {
        const float* Ain = (l == 0) ? x : (out1 + (size_t)(l - 1) * DIM);
        int lda          = (l == 0) ? DIM : OUT1_STRIDE;
        k_gemm<<<(N + 31) / 32, 256, 0, stream>>>(Ain, lda, Ws[l], hb, N);
        k_agg <<<(N + 3) / 4, 256, 0, stream>>>(hb, rowptr, csr_src, dinv,
                                                bs[l], out1, N, l);
    }
    k_pool<<<NGRAPHS, 384, 0, stream>>>(out1, gstart, out0);
}

// Round 7
// 349.198 us; speedup vs baseline: 3.0579x; 1.1633x over previous
//
#include <hip/hip_runtime.h>

#define NNODES 50000
#define NEDGES 800000
#define DIM 128
#define NGRAPHS 128
#define OUT1_STRIDE 384   // 3 layers * 128 concat along axis 1
#define OUT0_ELEMS (NGRAPHS * OUT1_STRIDE)
#define SCAN_CHUNK 512
#define ROWPAD 50048      // 64-aligned node row allocation

typedef unsigned int uint;
typedef unsigned short ushort;
typedef short bf16x8 __attribute__((ext_vector_type(8)));
typedef float f32x4 __attribute__((ext_vector_type(4)));

union U4 { uint4 u; bf16x8 h; };

__device__ inline uint rne_bf16(float f) {
    uint b = __float_as_uint(f);
    return (b + 0x7fffu + ((b >> 16) & 1u)) >> 16;
}
__device__ inline uint pack_bf16(float lo, float hi) {
    return rne_bf16(lo) | (rne_bf16(hi) << 16);
}

// ---------- CSR build ----------
__global__ void k_count(const int* __restrict__ dst, int* __restrict__ rowcnt,
                        int* __restrict__ rank, int E) {
    int e = blockIdx.x * blockDim.x + threadIdx.x;
    if (e < E) rank[e] = atomicAdd(&rowcnt[dst[e]], 1);
}

// per-chunk sum + fused dinv
__global__ __launch_bounds__(512) void k_sum(const int* __restrict__ cnt,
                                             int* __restrict__ bsum,
                                             float* __restrict__ dinv, int n) {
    __shared__ int red[512];
    int t = threadIdx.x;
    int i = blockIdx.x * SCAN_CHUNK + t;
    int c = (i < n) ? cnt[i] : 0;
    if (i < n) dinv[i] = rsqrtf((float)c + 1.0f);  // +1 self-loop
    red[t] = c;
    __syncthreads();
    for (int off = 256; off > 0; off >>= 1) {
        if (t < off) red[t] += red[t + off];
        __syncthreads();
    }
    if (t == 0) bsum[blockIdx.x] = red[0];
}

__global__ __launch_bounds__(128) void k_scanb(const int* __restrict__ bsum,
                                               int* __restrict__ boff, int nb) {
    __shared__ int s[128];
    int t = threadIdx.x;
    int v = (t < nb) ? bsum[t] : 0;
    s[t] = v;
    __syncthreads();
    for (int off = 1; off < 128; off <<= 1) {
        int u = (t >= off) ? s[t - off] : 0;
        __syncthreads();
        s[t] += u;
        __syncthreads();
    }
    boff[t] = s[t] - v;  // exclusive
    if (t == nb - 1) boff[nb] = s[t];
}

__global__ __launch_bounds__(512) void k_writeptr(const int* __restrict__ cnt,
                                                  const int* __restrict__ boff,
                                                  int* __restrict__ rowptr, int n) {
    __shared__ int s[512];
    int t = threadIdx.x;
    int i = blockIdx.x * SCAN_CHUNK + t;
    int v = (i < n) ? cnt[i] : 0;
    s[t] = v;
    __syncthreads();
    for (int off = 1; off < 512; off <<= 1) {
        int u = (t >= off) ? s[t - off] : 0;
        __syncthreads();
        s[t] += u;
        __syncthreads();
    }
    if (i < n) rowptr[i] = boff[blockIdx.x] + s[t] - v;
    if (i == n - 1) rowptr[n] = boff[blockIdx.x] + s[t];
}

__global__ void k_fill(const int* __restrict__ src, const int* __restrict__ dst,
                       const int* __restrict__ rowptr, const int* __restrict__ rank,
                       int* __restrict__ csr_src, int E) {
    int e = blockIdx.x * blockDim.x + threadIdx.x;
    if (e < E) {
        int d = dst[e];
        csr_src[rowptr[d] + rank[e]] = src[e];
    }
}

__global__ void k_bounds(const int* __restrict__ batch, int* __restrict__ start, int N) {
    int g = threadIdx.x;
    if (g > NGRAPHS) return;
    if (g == NGRAPHS) { start[g] = N; return; }
    int lo = 0, hi = N;
    while (lo < hi) {
        int mid = (lo + hi) >> 1;
        if (batch[mid] < g) lo = mid + 1; else hi = mid;
    }
    start[g] = lo;
}

// ---------- x (f32) -> packed bf16 ----------
__global__ void k_cast(const float* __restrict__ x, uint* __restrict__ xbf, int total) {
    int i = blockIdx.x * blockDim.x + threadIdx.x;
    if (i < total) {
        float2 v = ((const float2*)x)[i];
        xbf[i] = pack_bf16(v.x, v.y);
    }
}

// ---------- W -> MFMA B-fragment swizzled bf16, all 3 layers ----------
// fragment f = kblk*8 + ntile (32), lane (64), j (8):
//   value = W[kblk*32 + (lane>>4)*8 + j][ntile*16 + (lane&15)]
// stored contiguously: uint4 chunk index (f*64 + lane), 8 bf16 per chunk
__global__ __launch_bounds__(256) void k_wswz(const float* __restrict__ W0,
                                              const float* __restrict__ W1,
                                              const float* __restrict__ W2,
                                              uint* __restrict__ wz) {
    int layer = blockIdx.x >> 3;
    const float* W = (layer == 0) ? W0 : ((layer == 1) ? W1 : W2);
    int t = (blockIdx.x & 7) * 256 + threadIdx.x;  // chunk id 0..2047
    int f = t >> 6, lane = t & 63;
    int kb = f >> 3, nt = f & 7;
    int q = lane >> 4, m = lane & 15;
    int col = nt * 16 + m;
    uint v[8];
#pragma unroll
    for (int j = 0; j < 8; ++j)
        v[j] = rne_bf16(W[(kb * 32 + q * 8 + j) * 128 + col]);
    uint4 o;
    o.x = v[0] | (v[1] << 16);
    o.y = v[2] | (v[3] << 16);
    o.z = v[4] | (v[5] << 16);
    o.w = v[6] | (v[7] << 16);
    ((uint4*)wz)[layer * 2048 + t] = o;
}

// ---------- MFMA GEMM: hb[M x 128 bf16] = Abf[M x 128 bf16] @ W ----------
// 64 rows/block (16/wave); A fragments loaded straight from global (coalesced);
// swizzled W staged in LDS; C bounced through LDS for uint4 stores.
__global__ __launch_bounds__(256) void k_gemm(const uint* __restrict__ Abf,
                                              const uint* __restrict__ Wswz,
                                              uint* __restrict__ hb, int M) {
    __shared__ uint4 wsw[2048];       // 32 KB swizzled W
    __shared__ ushort cbuf[64 * 128]; // 16 KB C bounce
    int tid = threadIdx.x;
#pragma unroll
    for (int i = 0; i < 8; ++i)
        wsw[i * 256 + tid] = ((const uint4*)Wswz)[i * 256 + tid];
    __syncthreads();
    int wave = tid >> 6, lane = tid & 63;
    int q = lane >> 4, m = lane & 15;
    int row0 = blockIdx.x * 64 + wave * 16;
    f32x4 zero = {0.0f, 0.0f, 0.0f, 0.0f};
    f32x4 acc[8];
#pragma unroll
    for (int i = 0; i < 8; ++i) acc[i] = zero;
    const uint4* Arow = (const uint4*)(Abf + (size_t)(row0 + m) * 64);
#pragma unroll
    for (int kb = 0; kb < 4; ++kb) {
        U4 a; a.u = Arow[kb * 4 + q];   // A[row0+m][kb*32 + q*8 .. +7]
#pragma unroll
        for (int nt = 0; nt < 8; ++nt) {
            U4 b; b.u = wsw[(kb * 8 + nt) * 64 + lane];
            acc[nt] = __builtin_amdgcn_mfma_f32_16x16x32_bf16(a.h, b.h, acc[nt], 0, 0, 0);
        }
    }
    // C/D: col = nt*16 + m, row = q*4 + r  (per-wave LDS region, wave-local ordering)
    ushort* cw = cbuf + wave * 16 * 128;
#pragma unroll
    for (int nt = 0; nt < 8; ++nt)
#pragma unroll
        for (int r = 0; r < 4; ++r)
            cw[(q * 4 + r) * 128 + nt * 16 + m] = (ushort)rne_bf16(acc[nt][r]);
    // read back coalesced, store uint4 (16 uint4 per row)
    const uint4* cr4 = (const uint4*)cw;
#pragma unroll
    for (int i = 0; i < 4; ++i) {
        int c = i * 64 + lane;           // chunk: row = c>>4, piece = c&15
        int grow = row0 + (c >> 4);
        uint4 v = cr4[c];
        if (grow < M) ((uint4*)hb)[(size_t)grow * 16 + (c & 15)] = v;
    }
}

// ---------- fused aggregate + bias + relu + write out1 (f32) + hbin (bf16) ----------
__global__ __launch_bounds__(256) void k_agg(const uint* __restrict__ hb,
                                             const int* __restrict__ rowptr,
                                             const int* __restrict__ csr_src,
                                             const float* __restrict__ dinv,
                                             const float* __restrict__ bias,
                                             float* __restrict__ out1,
                                             uint* __restrict__ hbin,
                                             int N, int layer) {
    int wave = threadIdx.x >> 6;
    int lane = threadIdx.x & 63;
    int n = blockIdx.x * 4 + wave;
    if (n >= N) return;
    float din = dinv[n];
    uint u = hb[(size_t)n * 64 + lane];
    float ax = __uint_as_float(u << 16)         * din;  // self-loop (din^2 total)
    float ay = __uint_as_float(u & 0xffff0000u) * din;
    int beg = rowptr[n], end = rowptr[n + 1];
    for (int base = beg; base < end; base += 64) {
        int cnt = min(64, end - base);
        int eidx = base + lane;
        int   smy = 0;
        float wmy = 0.0f;
        if (eidx < end) { smy = csr_src[eidx]; wmy = dinv[smy]; }
        int j = 0;
        for (; j + 4 <= cnt; j += 4) {
            int   s0 = __shfl(smy, j),     s1 = __shfl(smy, j + 1);
            int   s2 = __shfl(smy, j + 2), s3 = __shfl(smy, j + 3);
            float w0 = __shfl(wmy, j),     w1 = __shfl(wmy, j + 1);
            float w2 = __shfl(wmy, j + 2), w3 = __shfl(wmy, j + 3);
            uint u0 = hb[(size_t)s0 * 64 + lane];
            uint u1 = hb[(size_t)s1 * 64 + lane];
            uint u2 = hb[(size_t)s2 * 64 + lane];
            uint u3 = hb[(size_t)s3 * 64 + lane];
            ax += w0 * __uint_as_float(u0 << 16) + w1 * __uint_as_float(u1 << 16)
                + w2 * __uint_as_float(u2 << 16) + w3 * __uint_as_float(u3 << 16);
            ay += w0 * __uint_as_float(u0 & 0xffff0000u) + w1 * __uint_as_float(u1 & 0xffff0000u)
                + w2 * __uint_as_float(u2 & 0xffff0000u) + w3 * __uint_as_float(u3 & 0xffff0000u);
        }
        for (; j < cnt; ++j) {
            int   ss = __shfl(smy, j);
            float ww = __shfl(wmy, j);
            uint uu = hb[(size_t)ss * 64 + lane];
            ax += ww * __uint_as_float(uu << 16);
            ay += ww * __uint_as_float(uu & 0xffff0000u);
        }
    }
    float2 b = ((const float2*)bias)[lane];
    float ox = fmaxf(din * ax + b.x, 0.0f);
    float oy = fmaxf(din * ay + b.y, 0.0f);
    size_t o1 = (size_t)n * OUT1_STRIDE + layer * DIM + lane * 2;
    *(float2*)(out1 + o1) = make_float2(ox, oy);
    hbin[(size_t)n * 64 + lane] = pack_bf16(ox, oy);  // next layer's GEMM input
}

// ---------- mean-pool: one block per graph, 384 threads (one per channel) ----------
__global__ __launch_bounds__(384) void k_pool(const float* __restrict__ out1,
                                              const int* __restrict__ start,
                                              float* __restrict__ out0) {
    int g = blockIdx.x;
    int c = threadIdx.x;
    int beg = start[g], end = start[g + 1];
    float acc = 0.0f;
    int i = beg;
    for (; i + 4 <= end; i += 4) {
        float a0 = out1[(size_t)(i    ) * OUT1_STRIDE + c];
        float a1 = out1[(size_t)(i + 1) * OUT1_STRIDE + c];
        float a2 = out1[(size_t)(i + 2) * OUT1_STRIDE + c];
        float a3 = out1[(size_t)(i + 3) * OUT1_STRIDE + c];
        acc += a0 + a1 + a2 + a3;
    }
    for (; i < end; ++i) acc += out1[(size_t)i * OUT1_STRIDE + c];
    float cnt = (float)(end - beg);
    out0[(size_t)g * OUT1_STRIDE + c] = acc / fmaxf(cnt, 1.0f);
}

extern "C" void kernel_launch(void* const* d_in, const int* in_sizes, int n_in,
                              void* d_out, int out_size, void* d_ws, size_t ws_size,
                              hipStream_t stream) {
    const float* x     = (const float*)d_in[0];
    const int*   ei    = (const int*)d_in[1];
    const int*   batch = (const int*)d_in[2];
    const float* W0 = (const float*)d_in[3];
    const float* b0 = (const float*)d_in[4];
    const float* W1 = (const float*)d_in[5];
    const float* b1 = (const float*)d_in[6];
    const float* W2 = (const float*)d_in[7];
    const float* b2 = (const float*)d_in[8];
    (void)n_in; (void)ws_size; (void)out_size;

    const int E = in_sizes[1] / 2;
    const int N = in_sizes[2];
    const int* src = ei;
    const int* dst = ei + E;

    char* ws = (char*)d_ws;
    uint*  hb       = (uint*)ws;  ws += (size_t)ROWPAD * 64 * 4;   // bf16 h@W
    uint*  hbin     = (uint*)ws;  ws += (size_t)ROWPAD * 64 * 4;   // bf16 layer input
    uint*  xbf      = (uint*)ws;  ws += (size_t)ROWPAD * 64 * 4;   // bf16 x
    uint*  wz       = (uint*)ws;  ws += 3 * 8192 * 4;              // swizzled W ×3
    float* dinv     = (float*)ws; ws += 50016 * 4;
    int*   rowcnt   = (int*)ws;   ws += 50016 * 4;
    int*   rowptr   = (int*)ws;   ws += 50016 * 4;
    int*   rank     = (int*)ws;   ws += (size_t)NEDGES * 4;
    int*   csr_src  = (int*)ws;   ws += (size_t)NEDGES * 4;
    int*   gstart   = (int*)ws;   ws += 256 * 4;
    int*   bsum     = (int*)ws;   ws += 256 * 4;
    int*   boff     = (int*)ws;   ws += 256 * 4;

    float* out0 = (float*)d_out;                 // [128, 384] pooled
    float* out1 = (float*)d_out + OUT0_ELEMS;    // [50000, 384] per-layer features

    const int nb = (N + SCAN_CHUNK - 1) / SCAN_CHUNK;  // 98

    hipMemsetAsync(rowcnt, 0, (size_t)N * 4, stream);

    k_count   <<<(E + 255) / 256, 256, 0, stream>>>(dst, rowcnt, rank, E);
    k_sum     <<<nb, 512, 0, stream>>>(rowcnt, bsum, dinv, N);
    k_scanb   <<<1, 128, 0, stream>>>(bsum, boff, nb);
    k_writeptr<<<nb, 512, 0, stream>>>(rowcnt, boff, rowptr, N);
    k_fill    <<<(E + 255) / 256, 256, 0, stream>>>(src, dst, rowptr, rank, csr_src, E);
    k_bounds  <<<1, 256, 0, stream>>>(batch, gstart, N);
    k_cast    <<<(N * 64 + 255) / 256, 256, 0, stream>>>(x, xbf, N * 64);
    k_wswz    <<<24, 256, 0, stream>>>(W0, W1, W2, wz);

    const float* bs[3] = {b0, b1, b2};
    const int ngb = (N + 63) / 64;   // 782 gemm blocks
    for (int l = 0; l < 3; ++l) {
        const uint* Ain = (l == 0) ? xbf : hbin;
        k_gemm<<<ngb, 256, 0, stream>>>(Ain, wz + l * 8192, hb, N);
        k_agg <<<(N + 3) / 4, 256, 0, stream>>>(hb, rowptr, csr_src, dinv,
                                                bs[l], out1, hbin, N, l);
    }
    k_pool<<<NGRAPHS, 384, 0, stream>>>(out1, gstart, out0);
}

// Round 9
// 329.783 us; speedup vs baseline: 3.2379x; 1.0589x over previous
//
#include <hip/hip_runtime.h>

#define NNODES 50000
#define NEDGES 800000
#define DIM 128
#define NGRAPHS 128
#define OUT1_STRIDE 384   // 3 layers * 128 concat along axis 1
#define OUT0_ELEMS (NGRAPHS * OUT1_STRIDE)
#define SCAN_CHUNK 512
#define ROWPAD 50048      // 64-aligned node row allocation

typedef unsigned int uint;
typedef unsigned short ushort;
typedef short bf16x8 __attribute__((ext_vector_type(8)));
typedef float f32x4 __attribute__((ext_vector_type(4)));

union U4 { uint4 u; bf16x8 h; };

__device__ inline uint rne_bf16(float f) {
    uint b = __float_as_uint(f);
    return (b + 0x7fffu + ((b >> 16) & 1u)) >> 16;
}
__device__ inline uint pack_bf16(float lo, float hi) {
    return rne_bf16(lo) | (rne_bf16(hi) << 16);
}
__device__ inline float blo(uint u) { return __uint_as_float(u << 16); }
__device__ inline float bhi(uint u) { return __uint_as_float(u & 0xffff0000u); }

// ---------- pre: W swizzle (blocks 0..23) + rowcnt zero (blocks 24..) ----------
// W -> MFMA B-fragment bf16: frag f = kblk*8+ntile, lane, j:
//   value = W[kblk*32 + (lane>>4)*8 + j][ntile*16 + (lane&15)]
__global__ __launch_bounds__(256) void k_pre(const float* __restrict__ W0,
                                             const float* __restrict__ W1,
                                             const float* __restrict__ W2,
                                             uint* __restrict__ wz,
                                             int* __restrict__ rowcnt, int N) {
    if (blockIdx.x >= 24) {
        int i = (blockIdx.x - 24) * 256 + threadIdx.x;
        if (i < N) rowcnt[i] = 0;
        return;
    }
    int layer = blockIdx.x >> 3;
    const float* W = (layer == 0) ? W0 : ((layer == 1) ? W1 : W2);
    int t = (blockIdx.x & 7) * 256 + threadIdx.x;  // chunk id 0..2047
    int f = t >> 6, lane = t & 63;
    int kb = f >> 3, nt = f & 7;
    int q = lane >> 4, m = lane & 15;
    int col = nt * 16 + m;
    uint v[8];
#pragma unroll
    for (int j = 0; j < 8; ++j)
        v[j] = rne_bf16(W[(kb * 32 + q * 8 + j) * 128 + col]);
    uint4 o;
    o.x = v[0] | (v[1] << 16);
    o.y = v[2] | (v[3] << 16);
    o.z = v[4] | (v[5] << 16);
    o.w = v[6] | (v[7] << 16);
    ((uint4*)wz)[layer * 2048 + t] = o;
}

// ---------- CSR build ----------
__global__ void k_count(const int* __restrict__ dst, int* __restrict__ rowcnt,
                        int* __restrict__ rank, int E) {
    int e = blockIdx.x * blockDim.x + threadIdx.x;
    if (e < E) rank[e] = atomicAdd(&rowcnt[dst[e]], 1);
}

__global__ __launch_bounds__(512) void k_sum(const int* __restrict__ cnt,
                                             int* __restrict__ bsum,
                                             float* __restrict__ dinv, int n) {
    __shared__ int red[512];
    int t = threadIdx.x;
    int i = blockIdx.x * SCAN_CHUNK + t;
    int c = (i < n) ? cnt[i] : 0;
    if (i < n) dinv[i] = rsqrtf((float)c + 1.0f);  // +1 self-loop
    red[t] = c;
    __syncthreads();
    for (int off = 256; off > 0; off >>= 1) {
        if (t < off) red[t] += red[t + off];
        __syncthreads();
    }
    if (t == 0) bsum[blockIdx.x] = red[0];
}

__global__ __launch_bounds__(128) void k_scanb(const int* __restrict__ bsum,
                                               int* __restrict__ boff, int nb) {
    __shared__ int s[128];
    int t = threadIdx.x;
    int v = (t < nb) ? bsum[t] : 0;
    s[t] = v;
    __syncthreads();
    for (int off = 1; off < 128; off <<= 1) {
        int u = (t >= off) ? s[t - off] : 0;
        __syncthreads();
        s[t] += u;
        __syncthreads();
    }
    boff[t] = s[t] - v;  // exclusive
    if (t == nb - 1) boff[nb] = s[t];
}

__global__ __launch_bounds__(512) void k_writeptr(const int* __restrict__ cnt,
                                                  const int* __restrict__ boff,
                                                  int* __restrict__ rowptr, int n) {
    __shared__ int s[512];
    int t = threadIdx.x;
    int i = blockIdx.x * SCAN_CHUNK + t;
    int v = (i < n) ? cnt[i] : 0;
    s[t] = v;
    __syncthreads();
    for (int off = 1; off < 512; off <<= 1) {
        int u = (t >= off) ? s[t - off] : 0;
        __syncthreads();
        s[t] += u;
        __syncthreads();
    }
    if (i < n) rowptr[i] = boff[blockIdx.x] + s[t] - v;
    if (i == n - 1) rowptr[n] = boff[blockIdx.x] + s[t];
}

__global__ void k_fill(const int* __restrict__ src, const int* __restrict__ dst,
                       const int* __restrict__ rowptr, const int* __restrict__ rank,
                       int* __restrict__ csr_src, int E) {
    int e = blockIdx.x * blockDim.x + threadIdx.x;
    if (e < E) {
        int d = dst[e];
        csr_src[rowptr[d] + rank[e]] = src[e];
    }
}

// ---------- MFMA GEMM: hb[M x 128 bf16] = A[M x 128 f32, stride lda] @ W ----------
// 64 rows/block; A read from global f32 and converted in-register; swizzled W in LDS.
__global__ __launch_bounds__(256) void k_gemm(const float* __restrict__ A, int lda,
                                              const uint* __restrict__ Wswz,
                                              uint* __restrict__ hb, int M) {
    __shared__ uint4 wsw[2048];       // 32 KB swizzled W
    __shared__ ushort cbuf[64 * 128]; // 16 KB C bounce
    int tid = threadIdx.x;
#pragma unroll
    for (int i = 0; i < 8; ++i)
        wsw[i * 256 + tid] = ((const uint4*)Wswz)[i * 256 + tid];
    __syncthreads();
    int wave = tid >> 6, lane = tid & 63;
    int q = lane >> 4, m = lane & 15;
    int row0 = blockIdx.x * 64 + wave * 16;
    int arow = min(row0 + m, M - 1);       // clamp; stores are guarded
    const float* Ar = A + (size_t)arow * lda + q * 8;
    f32x4 zero = {0.0f, 0.0f, 0.0f, 0.0f};
    f32x4 acc[8];
#pragma unroll
    for (int i = 0; i < 8; ++i) acc[i] = zero;
#pragma unroll
    for (int kb = 0; kb < 4; ++kb) {
        float4 f0 = *(const float4*)(Ar + kb * 32);
        float4 f1 = *(const float4*)(Ar + kb * 32 + 4);
        U4 a;
        a.u.x = pack_bf16(f0.x, f0.y);
        a.u.y = pack_bf16(f0.z, f0.w);
        a.u.z = pack_bf16(f1.x, f1.y);
        a.u.w = pack_bf16(f1.z, f1.w);
#pragma unroll
        for (int nt = 0; nt < 8; ++nt) {
            U4 b; b.u = wsw[(kb * 8 + nt) * 64 + lane];
            acc[nt] = __builtin_amdgcn_mfma_f32_16x16x32_bf16(a.h, b.h, acc[nt], 0, 0, 0);
        }
    }
    // C/D: col = nt*16 + m, row = q*4 + r
    ushort* cw = cbuf + wave * 16 * 128;
#pragma unroll
    for (int nt = 0; nt < 8; ++nt)
#pragma unroll
        for (int r = 0; r < 4; ++r)
            cw[(q * 4 + r) * 128 + nt * 16 + m] = (ushort)rne_bf16(acc[nt][r]);
    const uint4* cr4 = (const uint4*)cw;
#pragma unroll
    for (int i = 0; i < 4; ++i) {
        int c = i * 64 + lane;           // chunk: row = c>>4, piece = c&15
        int grow = row0 + (c >> 4);
        uint4 v = cr4[c];
        if (grow < M) ((uint4*)hb)[(size_t)grow * 16 + (c & 15)] = v;
    }
}

// ---------- fused aggregate + bias + relu + write out1 ----------
// one wave per node; lane handles 2 channels (R7-proven uniform-shfl structure),
// unrolled x8 for memory-level parallelism.
__global__ __launch_bounds__(256) void k_agg(const uint* __restrict__ hb,
                                             const int* __restrict__ rowptr,
                                             const int* __restrict__ csr_src,
                                             const float* __restrict__ dinv,
                                             const float* __restrict__ bias,
                                             float* __restrict__ out1,
                                             int N, int layer) {
    int wave = threadIdx.x >> 6;
    int lane = threadIdx.x & 63;
    int n = blockIdx.x * 4 + wave;
    if (n >= N) return;
    float din = dinv[n];
    uint u = hb[(size_t)n * 64 + lane];
    float ax = blo(u) * din;   // self-loop (din^2 after epilogue mult)
    float ay = bhi(u) * din;
    int beg = rowptr[n], end = rowptr[n + 1];
    for (int base = beg; base < end; base += 64) {
        int cnt = min(64, end - base);
        int eidx = base + lane;
        int smy = 0; float wmy = 0.0f;
        if (eidx < end) { smy = csr_src[eidx]; wmy = dinv[smy]; }
        int j = 0;
        for (; j + 8 <= cnt; j += 8) {
            int   s0 = __shfl(smy, j),     s1 = __shfl(smy, j + 1);
            int   s2 = __shfl(smy, j + 2), s3 = __shfl(smy, j + 3);
            int   s4 = __shfl(smy, j + 4), s5 = __shfl(smy, j + 5);
            int   s6 = __shfl(smy, j + 6), s7 = __shfl(smy, j + 7);
            float w0 = __shfl(wmy, j),     w1 = __shfl(wmy, j + 1);
            float w2 = __shfl(wmy, j + 2), w3 = __shfl(wmy, j + 3);
            float w4 = __shfl(wmy, j + 4), w5 = __shfl(wmy, j + 5);
            float w6 = __shfl(wmy, j + 6), w7 = __shfl(wmy, j + 7);
            uint u0 = hb[(size_t)s0 * 64 + lane];
            uint u1 = hb[(size_t)s1 * 64 + lane];
            uint u2 = hb[(size_t)s2 * 64 + lane];
            uint u3 = hb[(size_t)s3 * 64 + lane];
            uint u4 = hb[(size_t)s4 * 64 + lane];
            uint u5 = hb[(size_t)s5 * 64 + lane];
            uint u6 = hb[(size_t)s6 * 64 + lane];
            uint u7 = hb[(size_t)s7 * 64 + lane];
            ax += w0 * blo(u0) + w1 * blo(u1) + w2 * blo(u2) + w3 * blo(u3)
                + w4 * blo(u4) + w5 * blo(u5) + w6 * blo(u6) + w7 * blo(u7);
            ay += w0 * bhi(u0) + w1 * bhi(u1) + w2 * bhi(u2) + w3 * bhi(u3)
                + w4 * bhi(u4) + w5 * bhi(u5) + w6 * bhi(u6) + w7 * bhi(u7);
        }
        for (; j + 4 <= cnt; j += 4) {
            int   s0 = __shfl(smy, j),     s1 = __shfl(smy, j + 1);
            int   s2 = __shfl(smy, j + 2), s3 = __shfl(smy, j + 3);
            float w0 = __shfl(wmy, j),     w1 = __shfl(wmy, j + 1);
            float w2 = __shfl(wmy, j + 2), w3 = __shfl(wmy, j + 3);
            uint u0 = hb[(size_t)s0 * 64 + lane];
            uint u1 = hb[(size_t)s1 * 64 + lane];
            uint u2 = hb[(size_t)s2 * 64 + lane];
            uint u3 = hb[(size_t)s3 * 64 + lane];
            ax += w0 * blo(u0) + w1 * blo(u1) + w2 * blo(u2) + w3 * blo(u3);
            ay += w0 * bhi(u0) + w1 * bhi(u1) + w2 * bhi(u2) + w3 * bhi(u3);
        }
        for (; j < cnt; ++j) {
            int   ss = __shfl(smy, j);
            float ww = __shfl(wmy, j);
            uint uu = hb[(size_t)ss * 64 + lane];
            ax += ww * blo(uu);
            ay += ww * bhi(uu);
        }
    }
    float2 b = ((const float2*)bias)[lane];
    float ox = fmaxf(din * ax + b.x, 0.0f);
    float oy = fmaxf(din * ay + b.y, 0.0f);
    size_t o1 = (size_t)n * OUT1_STRIDE + layer * DIM + lane * 2;
    *(float2*)(out1 + o1) = make_float2(ox, oy);
}

// ---------- mean-pool: one block per graph; bounds via in-kernel binary search ----------
__global__ __launch_bounds__(384) void k_pool(const float* __restrict__ out1,
                                              const int* __restrict__ batch,
                                              float* __restrict__ out0, int N) {
    int g = blockIdx.x;
    int lo = 0, hi = N;
    while (lo < hi) { int mid = (lo + hi) >> 1; if (batch[mid] < g) lo = mid + 1; else hi = mid; }
    int beg = lo;
    hi = N;
    while (lo < hi) { int mid = (lo + hi) >> 1; if (batch[mid] < g + 1) lo = mid + 1; else hi = mid; }
    int end = lo;
    int c = threadIdx.x;
    float acc = 0.0f;
    int i = beg;
    for (; i + 4 <= end; i += 4) {
        float a0 = out1[(size_t)(i    ) * OUT1_STRIDE + c];
        float a1 = out1[(size_t)(i + 1) * OUT1_STRIDE + c];
        float a2 = out1[(size_t)(i + 2) * OUT1_STRIDE + c];
        float a3 = out1[(size_t)(i + 3) * OUT1_STRIDE + c];
        acc += a0 + a1 + a2 + a3;
    }
    for (; i < end; ++i) acc += out1[(size_t)i * OUT1_STRIDE + c];
    float cnt = (float)(end - beg);
    out0[(size_t)g * OUT1_STRIDE + c] = acc / fmaxf(cnt, 1.0f);
}

extern "C" void kernel_launch(void* const* d_in, const int* in_sizes, int n_in,
                              void* d_out, int out_size, void* d_ws, size_t ws_size,
                              hipStream_t stream) {
    const float* x     = (const float*)d_in[0];
    const int*   ei    = (const int*)d_in[1];
    const int*   batch = (const int*)d_in[2];
    const float* W0 = (const float*)d_in[3];
    const float* b0 = (const float*)d_in[4];
    const float* W1 = (const float*)d_in[5];
    const float* b1 = (const float*)d_in[6];
    const float* W2 = (const float*)d_in[7];
    const float* b2 = (const float*)d_in[8];
    (void)n_in; (void)ws_size; (void)out_size;

    const int E = in_sizes[1] / 2;
    const int N = in_sizes[2];
    const int* src = ei;
    const int* dst = ei + E;

    char* ws = (char*)d_ws;
    uint*  hb       = (uint*)ws;  ws += (size_t)ROWPAD * 64 * 4;   // bf16 h@W
    uint*  wz       = (uint*)ws;  ws += 3 * 8192 * 4;              // swizzled W ×3
    float* dinv     = (float*)ws; ws += 50016 * 4;
    int*   rowcnt   = (int*)ws;   ws += 50016 * 4;
    int*   rowptr   = (int*)ws;   ws += 50016 * 4;
    int*   rank     = (int*)ws;   ws += (size_t)NEDGES * 4;
    int*   csr_src  = (int*)ws;   ws += (size_t)NEDGES * 4;
    int*   bsum     = (int*)ws;   ws += 256 * 4;
    int*   boff     = (int*)ws;   ws += 256 * 4;

    float* out0 = (float*)d_out;                 // [128, 384] pooled
    float* out1 = (float*)d_out + OUT0_ELEMS;    // [50000, 384] per-layer features

    const int nb  = (N + SCAN_CHUNK - 1) / SCAN_CHUNK;  // 98
    const int nbz = 24 + (N + 255) / 256;               // pre: 24 wswz + zero blocks

    k_pre     <<<nbz, 256, 0, stream>>>(W0, W1, W2, wz, rowcnt, N);
    k_count   <<<(E + 255) / 256, 256, 0, stream>>>(dst, rowcnt, rank, E);
    k_sum     <<<nb, 512, 0, stream>>>(rowcnt, bsum, dinv, N);
    k_scanb   <<<1, 128, 0, stream>>>(bsum, boff, nb);
    k_writeptr<<<nb, 512, 0, stream>>>(rowcnt, boff, rowptr, N);
    k_fill    <<<(E + 255) / 256, 256, 0, stream>>>(src, dst, rowptr, rank, csr_src, E);

    const float* bs[3] = {b0, b1, b2};
    const int ngb = (N + 63) / 64;   // 782 gemm blocks
    for (int l = 0; l < 3; ++l) {
        const float* Ain = (l == 0) ? x : (out1 + (size_t)(l - 1) * DIM);
        int lda          = (l == 0) ? DIM : OUT1_STRIDE;
        k_gemm<<<ngb, 256, 0, stream>>>(Ain, lda, wz + l * 8192, hb, N);
        k_agg <<<(N + 3) / 4, 256, 0, stream>>>(hb, rowptr, csr_src, dinv,
                                                bs[l], out1, N, l);
    }
    k_pool<<<NGRAPHS, 384, 0, stream>>>(out1, batch, out0, N);
}